// Round 3
// baseline (477.871 us; speedup 1.0000x reference)
//
#include <hip/hip_runtime.h>
#include <hip/hip_bf16.h>

// MHA: B=2, S=2048, N_FEAT=1024, H=16, D=64
// Pipeline: f32->bf16 converts; 3 proj GEMMs (bf16 MFMA, fused layout epilogue);
// flash attention (swapped QK^T, in-register P via 16x16x16 PV, XCD-local K/V);
// output GEMM.

typedef float f32x4 __attribute__((ext_vector_type(4)));
typedef short bf16x8 __attribute__((ext_vector_type(8)));
typedef short bf16x4 __attribute__((ext_vector_type(4)));

typedef const __attribute__((address_space(1))) void* gas_ptr;
typedef __attribute__((address_space(3))) void* las_ptr;

static __device__ __forceinline__ short to_bf16s(float f) {
    __hip_bfloat16 h = __float2bfloat16(f);
    return __builtin_bit_cast(short, h);
}
static __device__ __forceinline__ unsigned pack_bf16(float a, float b) {
    unsigned lo = (unsigned short)__builtin_bit_cast(short, __float2bfloat16(a));
    unsigned hi = (unsigned short)__builtin_bit_cast(short, __float2bfloat16(b));
    return lo | (hi << 16);
}
static __device__ __forceinline__ bf16x4 pack4(float a, float b, float c, float d) {
    unsigned long long u = (unsigned long long)pack_bf16(a, b)
                         | ((unsigned long long)pack_bf16(c, d) << 32);
    return __builtin_bit_cast(bf16x4, u);
}

// 16x16x16 bf16 MFMA: B-frag layout (col=lane&15, k=(lane>>4)*4+i) matches the
// swapped-QK^T C-layout exactly -> P stays in registers.
static __device__ __forceinline__ f32x4 mfma16(bf16x4 a, bf16x4 b, f32x4 c) {
#if __has_builtin(__builtin_amdgcn_mfma_f32_16x16x16bf16_1k)
    return __builtin_amdgcn_mfma_f32_16x16x16bf16_1k(a, b, c, 0, 0, 0);
#else
    asm("v_mfma_f32_16x16x16_bf16 %0, %1, %2, %0" : "+v"(c) : "v"(a), "v"(b));
    return c;
#endif
}

// ---------------- f32 -> bf16 conversion (vectorized x4) ----------------
__global__ void cvt_kernel(const float* __restrict__ src, short* __restrict__ dst, int n4) {
    int i = blockIdx.x * blockDim.x + threadIdx.x;
    if (i >= n4) return;
    float4 v = reinterpret_cast<const float4*>(src)[i];
    short4 o;
    o.x = to_bf16s(v.x);
    o.y = to_bf16s(v.y);
    o.z = to_bf16s(v.z);
    o.w = to_bf16s(v.w);
    reinterpret_cast<short4*>(dst)[i] = o;
}

// mask (int 0/1) -> additive float bias (0 or -10000, matching reference)
__global__ void maskf_kernel(const int* __restrict__ mask, float* __restrict__ mf) {
    int i = blockIdx.x * 256 + threadIdx.x;
    mf[i] = mask[i] ? -10000.0f : 0.0f;
}

// ---------------- GEMM: C = A @ W^T + bias ----------------
template <int EPI>
__global__ __launch_bounds__(256, 2) void gemm_nt(
    const short* __restrict__ A, const short* __restrict__ W,
    const float* __restrict__ bias, void* __restrict__ outp,
    int M, int N, int K)
{
    __shared__ __align__(16) short lds_a[128 * 32];
    __shared__ __align__(16) short lds_b[128 * 32];
    const int tid = threadIdx.x;
    const int w = tid >> 6, l = tid & 63;
    const int lr = l & 15, lh = l >> 4;
    const int m0 = blockIdx.x * 128, n0 = blockIdx.y * 128;
    const int wr = (w >> 1) * 64, wc = (w & 1) * 64;

    f32x4 acc[4][4] = {};

    const int idx0 = tid, idx1 = 256 + tid;
    const int r0 = idx0 >> 2, c0 = (idx0 & 3) * 8;
    const int r1 = idx1 >> 2, c1 = (idx1 & 3) * 8;
    const short* ga0 = A + (long)(m0 + r0) * K + c0;
    const short* ga1 = A + (long)(m0 + r1) * K + c1;
    const short* gb0 = W + (long)(n0 + r0) * K + c0;
    const short* gb1 = W + (long)(n0 + r1) * K + c1;

    for (int k0 = 0; k0 < K; k0 += 32) {
        __builtin_amdgcn_global_load_lds((gas_ptr)(ga0 + k0), (las_ptr)(lds_a + w * 512), 16, 0, 0);
        __builtin_amdgcn_global_load_lds((gas_ptr)(ga1 + k0), (las_ptr)(lds_a + 2048 + w * 512), 16, 0, 0);
        __builtin_amdgcn_global_load_lds((gas_ptr)(gb0 + k0), (las_ptr)(lds_b + w * 512), 16, 0, 0);
        __builtin_amdgcn_global_load_lds((gas_ptr)(gb1 + k0), (las_ptr)(lds_b + 2048 + w * 512), 16, 0, 0);
        __syncthreads();

        bf16x8 af[4], bfr[4];
#pragma unroll
        for (int i = 0; i < 4; ++i)
            af[i] = *reinterpret_cast<const bf16x8*>(lds_a + (wr + i * 16 + lr) * 32 + lh * 8);
#pragma unroll
        for (int i = 0; i < 4; ++i)
            bfr[i] = *reinterpret_cast<const bf16x8*>(lds_b + (wc + i * 16 + lr) * 32 + lh * 8);
#pragma unroll
        for (int i = 0; i < 4; ++i)
#pragma unroll
            for (int j = 0; j < 4; ++j)
                acc[i][j] = __builtin_amdgcn_mfma_f32_16x16x32_bf16(af[i], bfr[j], acc[i][j], 0, 0, 0);
        __syncthreads();
    }

#pragma unroll
    for (int i = 0; i < 4; ++i) {
#pragma unroll
        for (int j = 0; j < 4; ++j) {
#pragma unroll
            for (int r = 0; r < 4; ++r) {
                const int row = m0 + wr + i * 16 + lh * 4 + r;  // M index (b*2048+s)
                const int col = n0 + wc + j * 16 + lr;          // N index (h*64+d)
                float v = acc[i][j][r] + bias[col];
                if constexpr (EPI == 0) {
                    const int b = row >> 11, s = row & 2047;
                    const int h = col >> 6, d = col & 63;
                    ((short*)outp)[(((long)(b * 16 + h)) * 2048 + s) * 64 + d] = to_bf16s(v);
                } else if constexpr (EPI == 1) {
                    const int b = row >> 11, s = row & 2047;
                    const int h = col >> 6, d = col & 63;
                    ((short*)outp)[(((long)(b * 16 + h)) * 64 + d) * 2048 + s] = to_bf16s(v);
                } else {
                    ((float*)outp)[(long)row * N + col] = v;
                }
            }
        }
    }
}

// ---------------- flash attention (swapped QK^T, in-register P) ----------------
// 1D grid of 1024 blocks, XCD-remapped: xcd = id&7 serves bh in [xcd*4, xcd*4+4)
// -> 2MB K+V per XCD L2. 4 waves/block, wave w owns 16 q-rows. Zero LDS.

struct KV {
    bf16x8 k0lo, k0hi, k1lo, k1hi;  // two 16-key tiles, d 0-31 / 32-63
    bf16x4 v[4][2];                 // V^T[dblk*16+lr][keysub + lh*4 ..] for 2 key-subtiles
    f32x4 mb0, mb1;                 // mask bias for the two key tiles
};

static __device__ __forceinline__ void kv_load(KV& f, const short* Kbase, const short* Vbase,
                                               const float* mfp, int key0) {
    const short* Kp0 = Kbase + key0 * 64;
    f.k0lo = *reinterpret_cast<const bf16x8*>(Kp0);
    f.k0hi = *reinterpret_cast<const bf16x8*>(Kp0 + 32);
    const short* Kp1 = Kp0 + 16 * 64;
    f.k1lo = *reinterpret_cast<const bf16x8*>(Kp1);
    f.k1hi = *reinterpret_cast<const bf16x8*>(Kp1 + 32);
    const short* Vp = Vbase + key0;
#pragma unroll
    for (int dblk = 0; dblk < 4; ++dblk) {
        f.v[dblk][0] = *reinterpret_cast<const bf16x4*>(Vp + (long)dblk * 16 * 2048);
        f.v[dblk][1] = *reinterpret_cast<const bf16x4*>(Vp + (long)dblk * 16 * 2048 + 16);
    }
    f.mb0 = *reinterpret_cast<const f32x4*>(mfp + key0);
    f.mb1 = *reinterpret_cast<const f32x4*>(mfp + key0 + 16);
}

static __device__ __forceinline__ void kv_step(const KV& f, bf16x8 qf0, bf16x8 qf1,
                                               float& m, float& ls, f32x4 ao[4]) {
    f32x4 sc0 = {}, sc1 = {};
    __builtin_amdgcn_s_setprio(1);
    sc0 = __builtin_amdgcn_mfma_f32_16x16x32_bf16(f.k0lo, qf0, sc0, 0, 0, 0);
    sc0 = __builtin_amdgcn_mfma_f32_16x16x32_bf16(f.k0hi, qf1, sc0, 0, 0, 0);
    sc1 = __builtin_amdgcn_mfma_f32_16x16x32_bf16(f.k1lo, qf0, sc1, 0, 0, 0);
    sc1 = __builtin_amdgcn_mfma_f32_16x16x32_bf16(f.k1hi, qf1, sc1, 0, 0, 0);
    __builtin_amdgcn_s_setprio(0);

    float s0[4], s1[4];
#pragma unroll
    for (int r = 0; r < 4; ++r) {
        s0[r] = sc0[r] * 0.125f + f.mb0[r];
        s1[r] = sc1[r] * 0.125f + f.mb1[r];
    }
    float t = fmaxf(fmaxf(fmaxf(s0[0], s0[1]), fmaxf(s0[2], s0[3])),
                    fmaxf(fmaxf(s1[0], s1[1]), fmaxf(s1[2], s1[3])));
    t = fmaxf(t, __shfl_xor(t, 16));
    t = fmaxf(t, __shfl_xor(t, 32));
    const float mn = fmaxf(m, t);
    const float sf = __expf(m - mn);
    float p0[4], p1[4], ps = 0.f;
#pragma unroll
    for (int r = 0; r < 4; ++r) {
        p0[r] = __expf(s0[r] - mn); ps += p0[r];
        p1[r] = __expf(s1[r] - mn); ps += p1[r];
    }
    ps += __shfl_xor(ps, 16);
    ps += __shfl_xor(ps, 32);
    ls = ls * sf + ps;
    m = mn;

    // P already sits in the 16x16x16 B-frag layout: k = 4*lh + r, col = lr.
    const bf16x4 pb0 = pack4(p0[0], p0[1], p0[2], p0[3]);
    const bf16x4 pb1 = pack4(p1[0], p1[1], p1[2], p1[3]);

#pragma unroll
    for (int dblk = 0; dblk < 4; ++dblk) ao[dblk] *= sf;

    __builtin_amdgcn_s_setprio(1);
#pragma unroll
    for (int dblk = 0; dblk < 4; ++dblk) {
        ao[dblk] = mfma16(f.v[dblk][0], pb0, ao[dblk]);
        ao[dblk] = mfma16(f.v[dblk][1], pb1, ao[dblk]);
    }
    __builtin_amdgcn_s_setprio(0);
}

__global__ __launch_bounds__(256, 3) void attn_kernel(
    const short* __restrict__ Q, const short* __restrict__ Kmat,
    const short* __restrict__ Vt, const float* __restrict__ maskf,
    short* __restrict__ X)
{
    // XCD-aware remap: id&7 = XCD -> 4 bh per XCD, all 32 q-blocks of each.
    const int id = blockIdx.x;
    const int slot = id >> 3;
    const int bh = (id & 7) * 4 + (slot >> 5);
    const int q0 = (slot & 31) * 64;
    const int b = bh >> 4, h = bh & 15;
    const int w = threadIdx.x >> 6, l = threadIdx.x & 63;
    const int lr = l & 15, lh = l >> 4;

    // Q B-frag: lane holds Q[q0 + w*16 + lr][d = lh*8 + i]
    const short* Qp = Q + ((long)bh * 2048 + q0 + w * 16 + lr) * 64 + lh * 8;
    const bf16x8 qf0 = *reinterpret_cast<const bf16x8*>(Qp);
    const bf16x8 qf1 = *reinterpret_cast<const bf16x8*>(Qp + 32);

    const short* Kbase = Kmat + (long)bh * 2048 * 64 + (long)lr * 64 + lh * 8;
    const short* Vbase = Vt + ((long)bh * 64 + lr) * 2048 + lh * 4;
    const float* mfp = maskf + b * 2048 + lh * 4;

    f32x4 ao[4] = {};
    float m = -1e30f, ls = 0.f;

    KV fA, fB;
    kv_load(fA, Kbase, Vbase, mfp, 0);
    for (int t = 0; t < 32; ++t) {
        const int key0 = t * 64;
        kv_load(fB, Kbase, Vbase, mfp, key0 + 32);
        kv_step(fA, qf0, qf1, m, ls, ao);
        if (t < 31) kv_load(fA, Kbase, Vbase, mfp, key0 + 64);
        kv_step(fB, qf0, qf1, m, ls, ao);
    }

    // lane holds O^T[d = dt*16 + lh*4 + r][q = lr]
    const float inv = 1.0f / fmaxf(ls, 1e-30f);
    const int s = q0 + w * 16 + lr;
    short* Xp = X + ((long)b * 2048 + s) * 1024 + h * 64 + lh * 4;
#pragma unroll
    for (int dt = 0; dt < 4; ++dt) {
        short4 o;
        o.x = to_bf16s(ao[dt][0] * inv);
        o.y = to_bf16s(ao[dt][1] * inv);
        o.z = to_bf16s(ao[dt][2] * inv);
        o.w = to_bf16s(ao[dt][3] * inv);
        *reinterpret_cast<short4*>(Xp + dt * 16) = o;
    }
}

// ---------------- launch ----------------
extern "C" void kernel_launch(void* const* d_in, const int* in_sizes, int n_in,
                              void* d_out, int out_size, void* d_ws, size_t ws_size,
                              hipStream_t stream) {
    const float* query = (const float*)d_in[0];
    const float* key_  = (const float*)d_in[1];
    const float* value = (const float*)d_in[2];
    const int*   mask  = (const int*)d_in[3];
    const float* w_q = (const float*)d_in[4];
    const float* b_q = (const float*)d_in[5];
    const float* w_k = (const float*)d_in[6];
    const float* b_k = (const float*)d_in[7];
    const float* w_v = (const float*)d_in[8];
    const float* b_v = (const float*)d_in[9];
    const float* w_o = (const float*)d_in[10];
    const float* b_o = (const float*)d_in[11];

    const long SEQ = 4194304;  // 4096*1024 elements
    const long WSZ = 1048576;  // 1024*1024
    short* ws = (short*)d_ws;
    short* cq = ws;            // converted query
    short* ck = cq + SEQ;
    short* cv = ck + SEQ;
    short* wq = cv + SEQ;
    short* wk = wq + WSZ;
    short* wv = wk + WSZ;
    short* wo = wv + WSZ;
    short* Qb = wo + WSZ;      // (B,H,S,64)
    short* Kb = Qb + SEQ;
    short* Vt = Kb + SEQ;      // (B,H,64,S)
    short* Xb = cq;            // reuse: cq dead after Q-projection
    float* mkf = (float*)cv;   // reuse: cv dead after V-projection (launched after)

    cvt_kernel<<<4096, 256, 0, stream>>>(query, cq, 1048576);
    cvt_kernel<<<4096, 256, 0, stream>>>(key_, ck, 1048576);
    cvt_kernel<<<4096, 256, 0, stream>>>(value, cv, 1048576);
    cvt_kernel<<<1024, 256, 0, stream>>>(w_q, wq, 262144);
    cvt_kernel<<<1024, 256, 0, stream>>>(w_k, wk, 262144);
    cvt_kernel<<<1024, 256, 0, stream>>>(w_v, wv, 262144);
    cvt_kernel<<<1024, 256, 0, stream>>>(w_o, wo, 262144);

    dim3 blk(256);
    dim3 gP(32, 8);  // M=4096 / 128, N=1024 / 128
    gemm_nt<0><<<gP, blk, 0, stream>>>(cq, wq, b_q, Qb, 4096, 1024, 1024);
    gemm_nt<0><<<gP, blk, 0, stream>>>(ck, wk, b_k, Kb, 4096, 1024, 1024);
    gemm_nt<1><<<gP, blk, 0, stream>>>(cv, wv, b_v, Vt, 4096, 1024, 1024);

    maskf_kernel<<<16, 256, 0, stream>>>(mask, mkf);  // after V GEMM (cv reuse)

    attn_kernel<<<1024, blk, 0, stream>>>(Qb, Kb, Vt, mkf, Xb);

    gemm_nt<2><<<gP, blk, 0, stream>>>(Xb, wo, b_o, d_out, 4096, 1024, 1024);
}

// Round 4
// 196.462 us; speedup vs baseline: 2.4324x; 2.4324x over previous
//
#include <hip/hip_runtime.h>
#include <hip/hip_bf16.h>

// MHA: B=2, S=2048, N_FEAT=1024, H=16, D=64
// Pipeline: f32->bf16 converts; 3 proj GEMMs (bf16 MFMA, fused layout epilogue);
// flash attention (LDS-staged double-buffered K/V, swapped QK^T, in-register P);
// output GEMM.

typedef float f32x4 __attribute__((ext_vector_type(4)));
typedef short bf16x8 __attribute__((ext_vector_type(8)));
typedef short bf16x4 __attribute__((ext_vector_type(4)));

typedef const __attribute__((address_space(1))) void* gas_ptr;
typedef __attribute__((address_space(3))) void* las_ptr;

static __device__ __forceinline__ short to_bf16s(float f) {
    __hip_bfloat16 h = __float2bfloat16(f);
    return __builtin_bit_cast(short, h);
}
static __device__ __forceinline__ unsigned pack_bf16(float a, float b) {
    unsigned lo = (unsigned short)__builtin_bit_cast(short, __float2bfloat16(a));
    unsigned hi = (unsigned short)__builtin_bit_cast(short, __float2bfloat16(b));
    return lo | (hi << 16);
}
static __device__ __forceinline__ bf16x4 pack4(float a, float b, float c, float d) {
    unsigned long long u = (unsigned long long)pack_bf16(a, b)
                         | ((unsigned long long)pack_bf16(c, d) << 32);
    return __builtin_bit_cast(bf16x4, u);
}

// 16x16x16 bf16 MFMA: B-frag layout (col=lane&15, k=(lane>>4)*4+i) matches the
// swapped-QK^T C-layout exactly -> P stays in registers. (HW-validated round 3.)
static __device__ __forceinline__ f32x4 mfma16(bf16x4 a, bf16x4 b, f32x4 c) {
#if __has_builtin(__builtin_amdgcn_mfma_f32_16x16x16bf16_1k)
    return __builtin_amdgcn_mfma_f32_16x16x16bf16_1k(a, b, c, 0, 0, 0);
#else
    asm("v_mfma_f32_16x16x16_bf16 %0, %1, %2, %0" : "+v"(c) : "v"(a), "v"(b));
    return c;
#endif
}

// ---------------- f32 -> bf16 conversion (vectorized x4) ----------------
__global__ void cvt_kernel(const float* __restrict__ src, short* __restrict__ dst, int n4) {
    int i = blockIdx.x * blockDim.x + threadIdx.x;
    if (i >= n4) return;
    float4 v = reinterpret_cast<const float4*>(src)[i];
    short4 o;
    o.x = to_bf16s(v.x);
    o.y = to_bf16s(v.y);
    o.z = to_bf16s(v.z);
    o.w = to_bf16s(v.w);
    reinterpret_cast<short4*>(dst)[i] = o;
}

// mask (int 0/1) -> additive float bias (0 or -10000, matching reference)
__global__ void maskf_kernel(const int* __restrict__ mask, float* __restrict__ mf) {
    int i = blockIdx.x * 256 + threadIdx.x;
    mf[i] = mask[i] ? -10000.0f : 0.0f;
}

// ---------------- GEMM: C = A @ W^T + bias ----------------
template <int EPI>
__global__ __launch_bounds__(256, 2) void gemm_nt(
    const short* __restrict__ A, const short* __restrict__ W,
    const float* __restrict__ bias, void* __restrict__ outp,
    int M, int N, int K)
{
    __shared__ __align__(16) short lds_a[128 * 32];
    __shared__ __align__(16) short lds_b[128 * 32];
    const int tid = threadIdx.x;
    const int w = tid >> 6, l = tid & 63;
    const int lr = l & 15, lh = l >> 4;
    const int m0 = blockIdx.x * 128, n0 = blockIdx.y * 128;
    const int wr = (w >> 1) * 64, wc = (w & 1) * 64;

    f32x4 acc[4][4] = {};

    const int idx0 = tid, idx1 = 256 + tid;
    const int r0 = idx0 >> 2, c0 = (idx0 & 3) * 8;
    const int r1 = idx1 >> 2, c1 = (idx1 & 3) * 8;
    const short* ga0 = A + (long)(m0 + r0) * K + c0;
    const short* ga1 = A + (long)(m0 + r1) * K + c1;
    const short* gb0 = W + (long)(n0 + r0) * K + c0;
    const short* gb1 = W + (long)(n0 + r1) * K + c1;

    for (int k0 = 0; k0 < K; k0 += 32) {
        __builtin_amdgcn_global_load_lds((gas_ptr)(ga0 + k0), (las_ptr)(lds_a + w * 512), 16, 0, 0);
        __builtin_amdgcn_global_load_lds((gas_ptr)(ga1 + k0), (las_ptr)(lds_a + 2048 + w * 512), 16, 0, 0);
        __builtin_amdgcn_global_load_lds((gas_ptr)(gb0 + k0), (las_ptr)(lds_b + w * 512), 16, 0, 0);
        __builtin_amdgcn_global_load_lds((gas_ptr)(gb1 + k0), (las_ptr)(lds_b + 2048 + w * 512), 16, 0, 0);
        __syncthreads();

        bf16x8 af[4], bfr[4];
#pragma unroll
        for (int i = 0; i < 4; ++i)
            af[i] = *reinterpret_cast<const bf16x8*>(lds_a + (wr + i * 16 + lr) * 32 + lh * 8);
#pragma unroll
        for (int i = 0; i < 4; ++i)
            bfr[i] = *reinterpret_cast<const bf16x8*>(lds_b + (wc + i * 16 + lr) * 32 + lh * 8);
#pragma unroll
        for (int i = 0; i < 4; ++i)
#pragma unroll
            for (int j = 0; j < 4; ++j)
                acc[i][j] = __builtin_amdgcn_mfma_f32_16x16x32_bf16(af[i], bfr[j], acc[i][j], 0, 0, 0);
        __syncthreads();
    }

#pragma unroll
    for (int i = 0; i < 4; ++i) {
#pragma unroll
        for (int j = 0; j < 4; ++j) {
#pragma unroll
            for (int r = 0; r < 4; ++r) {
                const int row = m0 + wr + i * 16 + lh * 4 + r;  // M index (b*2048+s)
                const int col = n0 + wc + j * 16 + lr;          // N index (h*64+d)
                float v = acc[i][j][r] + bias[col];
                if constexpr (EPI == 0) {
                    const int b = row >> 11, s = row & 2047;
                    const int h = col >> 6, d = col & 63;
                    ((short*)outp)[(((long)(b * 16 + h)) * 2048 + s) * 64 + d] = to_bf16s(v);
                } else if constexpr (EPI == 1) {
                    const int b = row >> 11, s = row & 2047;
                    const int h = col >> 6, d = col & 63;
                    ((short*)outp)[(((long)(b * 16 + h)) * 64 + d) * 2048 + s] = to_bf16s(v);
                } else {
                    ((float*)outp)[(long)row * N + col] = v;
                }
            }
        }
    }
}

// ---------------- flash attention v4 ----------------
// Grid 512 blocks (XCD-remapped: 4 heads/XCD -> 2MB K/V L2-resident).
// Block: 4 waves x 32 q-rows = 128 q-rows. KVBLK=64 keys/step, 32 steps.
// K tile [64 keys][64 d] and V^T tile [64 d][64 keys] staged in LDS via
// global_load_lds (16B), double-buffered, XOR-swizzled (chunk ^= row&7) with
// pre-swizzled global source (linear LDS dest). One barrier per step; stage
// for t+1 issued before compute(t) so HBM/L2 latency hides under MFMA.

static __device__ __forceinline__ void stage_kv(
    short* ldsKb, short* ldsVb, const short* Kg, const short* Vg,
    int key0, int w, int srow, int schunk)
{
    // K: rows = keys (contiguous 128B rows). V^T: rows = d (stride 2048 shorts).
    __builtin_amdgcn_global_load_lds((gas_ptr)(Kg + (long)(key0 + srow) * 64 + schunk * 8),
                                     (las_ptr)(ldsKb + w * 512), 16, 0, 0);
    __builtin_amdgcn_global_load_lds((gas_ptr)(Kg + (long)(key0 + srow + 32) * 64 + schunk * 8),
                                     (las_ptr)(ldsKb + 2048 + w * 512), 16, 0, 0);
    __builtin_amdgcn_global_load_lds((gas_ptr)(Vg + (long)srow * 2048 + key0 + schunk * 8),
                                     (las_ptr)(ldsVb + w * 512), 16, 0, 0);
    __builtin_amdgcn_global_load_lds((gas_ptr)(Vg + (long)(srow + 32) * 2048 + key0 + schunk * 8),
                                     (las_ptr)(ldsVb + 2048 + w * 512), 16, 0, 0);
}

static __device__ __forceinline__ void attn_step(
    const short* __restrict__ Kbuf, const short* __restrict__ Vbuf,
    const float* __restrict__ mfp, int key0,
    const bf16x8 (&qf)[2][2], int lr, int lh, int sw,
    float (&mreg)[2], float (&lsum)[2], f32x4 (&ao)[2][4])
{
    f32x4 mb[4];
#pragma unroll
    for (int s = 0; s < 4; ++s)
        mb[s] = *reinterpret_cast<const f32x4*>(mfp + key0 + s * 16);

    // QK^T swapped: sc[j][s] = K-subtile(s) . Q-frag(j); lane: q=lr, key=s*16+lh*4+r
    f32x4 sc[2][4];
#pragma unroll
    for (int s = 0; s < 4; ++s) {
        const short* kb = Kbuf + (s * 16 + lr) * 64;
        bf16x8 k0 = *reinterpret_cast<const bf16x8*>(kb + (((lh * 16) ^ sw) >> 1));
        bf16x8 k1 = *reinterpret_cast<const bf16x8*>(kb + (((64 + lh * 16) ^ sw) >> 1));
        f32x4 z = {};
        sc[0][s] = __builtin_amdgcn_mfma_f32_16x16x32_bf16(k0, qf[0][0], z, 0, 0, 0);
        sc[0][s] = __builtin_amdgcn_mfma_f32_16x16x32_bf16(k1, qf[0][1], sc[0][s], 0, 0, 0);
        sc[1][s] = __builtin_amdgcn_mfma_f32_16x16x32_bf16(k0, qf[1][0], z, 0, 0, 0);
        sc[1][s] = __builtin_amdgcn_mfma_f32_16x16x32_bf16(k1, qf[1][1], sc[1][s], 0, 0, 0);
    }

    bf16x4 pb[2][4];
#pragma unroll
    for (int j = 0; j < 2; ++j) {
        float t = -1e30f;
#pragma unroll
        for (int s = 0; s < 4; ++s)
#pragma unroll
            for (int r = 0; r < 4; ++r) {
                float v = sc[j][s][r] * 0.125f + mb[s][r];
                sc[j][s][r] = v;
                t = fmaxf(t, v);
            }
        t = fmaxf(t, __shfl_xor(t, 16));
        t = fmaxf(t, __shfl_xor(t, 32));
        const float mn = fmaxf(mreg[j], t);
        const float sf = __expf(mreg[j] - mn);
        float ps = 0.f;
#pragma unroll
        for (int s = 0; s < 4; ++s) {
            float p0 = __expf(sc[j][s][0] - mn);
            float p1 = __expf(sc[j][s][1] - mn);
            float p2 = __expf(sc[j][s][2] - mn);
            float p3 = __expf(sc[j][s][3] - mn);
            ps += (p0 + p1) + (p2 + p3);
            pb[j][s] = pack4(p0, p1, p2, p3);
        }
        ps += __shfl_xor(ps, 16);
        ps += __shfl_xor(ps, 32);
        lsum[j] = lsum[j] * sf + ps;
        mreg[j] = mn;
#pragma unroll
        for (int d4 = 0; d4 < 4; ++d4) ao[j][d4] *= sf;
    }

    // PV: ao[j][d4] += V^T-subtile(d4,s) . P(j,s); V frag shared across j
#pragma unroll
    for (int s = 0; s < 4; ++s) {
#pragma unroll
        for (int d4 = 0; d4 < 4; ++d4) {
            const short* vb = Vbuf + (d4 * 16 + lr) * 64;
            bf16x4 vf = *reinterpret_cast<const bf16x4*>(vb + (((s * 32 + lh * 8) ^ sw) >> 1));
            ao[0][d4] = mfma16(vf, pb[0][s], ao[0][d4]);
            ao[1][d4] = mfma16(vf, pb[1][s], ao[1][d4]);
        }
    }
}

__global__ __launch_bounds__(256) void attn_kernel(
    const short* __restrict__ Q, const short* __restrict__ Kmat,
    const short* __restrict__ Vt, const float* __restrict__ maskf,
    short* __restrict__ X)
{
    __shared__ __align__(16) short ldsK[2][4096];
    __shared__ __align__(16) short ldsV[2][4096];

    const int id = blockIdx.x;
    const int slot = id >> 3;
    const int bh = (id & 7) * 4 + (slot >> 4);   // XCD (id&7) serves heads 4x..4x+3
    const int q0 = (slot & 15) * 128;
    const int b = bh >> 4, h = bh & 15;
    const int w = threadIdx.x >> 6, l = threadIdx.x & 63;
    const int lr = l & 15, lh = l >> 4;
    const int sw = (lr & 7) << 4;                // read-side XOR swizzle (bytes)

    // staging geometry: lane covers tile row w*8 + l/8, 16B chunk (l&7)^(row&7)
    const int srow = w * 8 + (l >> 3);
    const int schunk = (l & 7) ^ (srow & 7);

    const short* Kg = Kmat + (long)bh * 2048 * 64;
    const short* Vg = Vt + (long)bh * 64 * 2048;
    const float* mfp = maskf + b * 2048 + lh * 4;

    // Q B-frags: 2 q-subtiles x 2 k-halves; lane: q-col=lr, k=lh*8+i
    const short* Qp = Q + ((long)bh * 2048 + q0 + w * 32 + lr) * 64 + lh * 8;
    bf16x8 qf[2][2];
    qf[0][0] = *reinterpret_cast<const bf16x8*>(Qp);
    qf[0][1] = *reinterpret_cast<const bf16x8*>(Qp + 32);
    qf[1][0] = *reinterpret_cast<const bf16x8*>(Qp + 16 * 64);
    qf[1][1] = *reinterpret_cast<const bf16x8*>(Qp + 16 * 64 + 32);

    float mreg[2] = {-1e30f, -1e30f}, lsum[2] = {0.f, 0.f};
    f32x4 ao[2][4] = {};

    stage_kv(ldsK[0], ldsV[0], Kg, Vg, 0, w, srow, schunk);
    __syncthreads();

    for (int tt = 0; tt < 16; ++tt) {
        const int key0 = tt * 128;
        stage_kv(ldsK[1], ldsV[1], Kg, Vg, key0 + 64, w, srow, schunk);
        attn_step(ldsK[0], ldsV[0], mfp, key0, qf, lr, lh, sw, mreg, lsum, ao);
        __syncthreads();
        if (tt < 15)
            stage_kv(ldsK[0], ldsV[0], Kg, Vg, key0 + 128, w, srow, schunk);
        attn_step(ldsK[1], ldsV[1], mfp, key0 + 64, qf, lr, lh, sw, mreg, lsum, ao);
        __syncthreads();
    }

    // lane holds O^T[d = d4*16 + lh*4 + r][q = lr] per q-subtile j
#pragma unroll
    for (int j = 0; j < 2; ++j) {
        const float inv = 1.0f / fmaxf(lsum[j], 1e-30f);
        const int s = q0 + w * 32 + j * 16 + lr;
        short* Xp = X + ((long)b * 2048 + s) * 1024 + h * 64 + lh * 4;
#pragma unroll
        for (int d4 = 0; d4 < 4; ++d4) {
            short4 o;
            o.x = to_bf16s(ao[j][d4][0] * inv);
            o.y = to_bf16s(ao[j][d4][1] * inv);
            o.z = to_bf16s(ao[j][d4][2] * inv);
            o.w = to_bf16s(ao[j][d4][3] * inv);
            *reinterpret_cast<short4*>(Xp + d4 * 16) = o;
        }
    }
}

// ---------------- launch ----------------
extern "C" void kernel_launch(void* const* d_in, const int* in_sizes, int n_in,
                              void* d_out, int out_size, void* d_ws, size_t ws_size,
                              hipStream_t stream) {
    const float* query = (const float*)d_in[0];
    const float* key_  = (const float*)d_in[1];
    const float* value = (const float*)d_in[2];
    const int*   mask  = (const int*)d_in[3];
    const float* w_q = (const float*)d_in[4];
    const float* b_q = (const float*)d_in[5];
    const float* w_k = (const float*)d_in[6];
    const float* b_k = (const float*)d_in[7];
    const float* w_v = (const float*)d_in[8];
    const float* b_v = (const float*)d_in[9];
    const float* w_o = (const float*)d_in[10];
    const float* b_o = (const float*)d_in[11];

    const long SEQ = 4194304;  // 4096*1024 elements
    const long WSZ = 1048576;  // 1024*1024
    short* ws = (short*)d_ws;
    short* cq = ws;            // converted query
    short* ck = cq + SEQ;
    short* cv = ck + SEQ;
    short* wq = cv + SEQ;
    short* wk = wq + WSZ;
    short* wv = wk + WSZ;
    short* wo = wv + WSZ;
    short* Qb = wo + WSZ;      // (B,H,S,64)
    short* Kb = Qb + SEQ;
    short* Vt = Kb + SEQ;      // (B,H,64,S)
    short* Xb = cq;            // reuse: cq dead after Q-projection
    float* mkf = (float*)cv;   // reuse: cv dead after V-projection (launched after)

    cvt_kernel<<<4096, 256, 0, stream>>>(query, cq, 1048576);
    cvt_kernel<<<4096, 256, 0, stream>>>(key_, ck, 1048576);
    cvt_kernel<<<4096, 256, 0, stream>>>(value, cv, 1048576);
    cvt_kernel<<<1024, 256, 0, stream>>>(w_q, wq, 262144);
    cvt_kernel<<<1024, 256, 0, stream>>>(w_k, wk, 262144);
    cvt_kernel<<<1024, 256, 0, stream>>>(w_v, wv, 262144);
    cvt_kernel<<<1024, 256, 0, stream>>>(w_o, wo, 262144);

    dim3 blk(256);
    dim3 gP(32, 8);  // M=4096 / 128, N=1024 / 128
    gemm_nt<0><<<gP, blk, 0, stream>>>(cq, wq, b_q, Qb, 4096, 1024, 1024);
    gemm_nt<0><<<gP, blk, 0, stream>>>(ck, wk, b_k, Kb, 4096, 1024, 1024);
    gemm_nt<1><<<gP, blk, 0, stream>>>(cv, wv, b_v, Vt, 4096, 1024, 1024);

    maskf_kernel<<<16, 256, 0, stream>>>(mask, mkf);  // after V GEMM (cv reuse)

    attn_kernel<<<512, blk, 0, stream>>>(Qb, Kb, Vt, mkf, Xb);

    gemm_nt<2><<<gP, blk, 0, stream>>>(Xb, wo, b_o, d_out, 4096, 1024, 1024);
}

// Round 5
// 148.025 us; speedup vs baseline: 3.2283x; 1.3272x over previous
//
#include <hip/hip_runtime.h>
#include <hip/hip_bf16.h>

// MHA: B=2, S=2048, N_FEAT=1024, H=16, D=64
// r5: fused 3-proj GEMM (768 blocks, dbuf 2-phase, rowpair-interleaved LDS);
//     attn: exp2-domain softmax (scale folded into Q), defer-max, mask in LDS.

typedef float f32x4 __attribute__((ext_vector_type(4)));
typedef short bf16x8 __attribute__((ext_vector_type(8)));
typedef short bf16x4 __attribute__((ext_vector_type(4)));

typedef const __attribute__((address_space(1))) void* gas_ptr;
typedef __attribute__((address_space(3))) void* las_ptr;

#if __has_builtin(__builtin_amdgcn_exp2f)
#define EXP2(x) __builtin_amdgcn_exp2f(x)
#else
#define EXP2(x) exp2f(x)
#endif
#define LOG2E 1.4426950408889634f

static __device__ __forceinline__ short to_bf16s(float f) {
    __hip_bfloat16 h = __float2bfloat16(f);
    return __builtin_bit_cast(short, h);
}
static __device__ __forceinline__ unsigned pack_bf16(float a, float b) {
    unsigned lo = (unsigned short)__builtin_bit_cast(short, __float2bfloat16(a));
    unsigned hi = (unsigned short)__builtin_bit_cast(short, __float2bfloat16(b));
    return lo | (hi << 16);
}
static __device__ __forceinline__ bf16x4 pack4(float a, float b, float c, float d) {
    unsigned long long u = (unsigned long long)pack_bf16(a, b)
                         | ((unsigned long long)pack_bf16(c, d) << 32);
    return __builtin_bit_cast(bf16x4, u);
}
static __device__ __forceinline__ f32x4 mfma16(bf16x4 a, bf16x4 b, f32x4 c) {
#if __has_builtin(__builtin_amdgcn_mfma_f32_16x16x16bf16_1k)
    return __builtin_amdgcn_mfma_f32_16x16x16bf16_1k(a, b, c, 0, 0, 0);
#else
    asm("v_mfma_f32_16x16x16_bf16 %0, %1, %2, %0" : "+v"(c) : "v"(a), "v"(b));
    return c;
#endif
}

// ---------------- conversions ----------------
__global__ void cvt3_kernel(const float* __restrict__ s0, const float* __restrict__ s1,
                            const float* __restrict__ s2, short* __restrict__ d0,
                            short* __restrict__ d1, short* __restrict__ d2) {
    const int g = blockIdx.x;
    const int sel = g >> 12;                      // 4096 blocks per tensor
    const int i = (g & 4095) * 256 + threadIdx.x; // n4 = 1048576
    const float* s = sel == 0 ? s0 : (sel == 1 ? s1 : s2);
    short* d = sel == 0 ? d0 : (sel == 1 ? d1 : d2);
    float4 v = reinterpret_cast<const float4*>(s)[i];
    short4 o;
    o.x = to_bf16s(v.x); o.y = to_bf16s(v.y); o.z = to_bf16s(v.z); o.w = to_bf16s(v.w);
    reinterpret_cast<short4*>(d)[i] = o;
}
__global__ void cvt4_kernel(const float* __restrict__ s0, const float* __restrict__ s1,
                            const float* __restrict__ s2, const float* __restrict__ s3,
                            short* __restrict__ d0, short* __restrict__ d1,
                            short* __restrict__ d2, short* __restrict__ d3) {
    const int g = blockIdx.x;
    const int sel = g >> 10;                      // 1024 blocks per tensor
    const int i = (g & 1023) * 256 + threadIdx.x; // n4 = 262144
    const float* s = sel == 0 ? s0 : (sel == 1 ? s1 : (sel == 2 ? s2 : s3));
    short* d = sel == 0 ? d0 : (sel == 1 ? d1 : (sel == 2 ? d2 : d3));
    float4 v = reinterpret_cast<const float4*>(s)[i];
    short4 o;
    o.x = to_bf16s(v.x); o.y = to_bf16s(v.y); o.z = to_bf16s(v.z); o.w = to_bf16s(v.w);
    reinterpret_cast<short4*>(d)[i] = o;
}

// mask (int 0/1) -> additive bias in log2 domain (0 or -10000*log2e)
__global__ void maskf_kernel(const int* __restrict__ mask, float* __restrict__ mf) {
    int i = blockIdx.x * 256 + threadIdx.x;
    mf[i] = mask[i] ? (-10000.0f * LOG2E) : 0.0f;
}

// ---------------- GEMM core: 128x128 tile, BK=32, dbuf 2-phase ----------------
// LDS rowpair-interleaved layout: row r, 16B-chunk c stored at 16B-unit
// (r>>1)*8 + c*2 + (r&1).  Reads (b128 at k=lh*8) hit all 32 banks uniformly;
// staging via global_load_lds stays lane-linear.

static __device__ __forceinline__ void stage_tile(
    short* sa, short* sb, const short* A, const short* W,
    int m0, int n0, int k0, int tid)
{
#pragma unroll
    for (int rnd = 0; rnd < 2; ++rnd) {
        const int t = rnd * 256 + tid;
        const int c2 = t & 7;
        const int row = 2 * (t >> 3) + (c2 & 1);
        const int col = (c2 >> 1) * 8;
        __builtin_amdgcn_global_load_lds((gas_ptr)(A + (long)(m0 + row) * 1024 + k0 + col),
                                         (las_ptr)(sa + t * 8), 16, 0, 0);
        __builtin_amdgcn_global_load_lds((gas_ptr)(W + (long)(n0 + row) * 1024 + k0 + col),
                                         (las_ptr)(sb + t * 8), 16, 0, 0);
    }
}

static __device__ __forceinline__ void gemm_compute(
    const short* sa, const short* sb, int wr, int wc, int aoff, f32x4 (&acc)[4][4])
{
    bf16x8 af[4], bfr[4];
#pragma unroll
    for (int i = 0; i < 4; ++i)
        af[i] = *reinterpret_cast<const bf16x8*>(sa + (wr + i * 16) * 32 + aoff);
#pragma unroll
    for (int j = 0; j < 4; ++j)
        bfr[j] = *reinterpret_cast<const bf16x8*>(sb + (wc + j * 16) * 32 + aoff);
#pragma unroll
    for (int i = 0; i < 4; ++i)
#pragma unroll
        for (int j = 0; j < 4; ++j)
            acc[i][j] = __builtin_amdgcn_mfma_f32_16x16x32_bf16(af[i], bfr[j], acc[i][j], 0, 0, 0);
}

// fused Q/K/V projection: blockIdx.z selects; Q scaled by 0.125*log2e;
// out layouts: z<2 -> (B,H,S,64) bf16; z==2 -> (B,H,64,S) bf16 (V^T)
__global__ __launch_bounds__(256, 3) void proj_gemm(
    const short* __restrict__ A0, const short* __restrict__ A1, const short* __restrict__ A2,
    const short* __restrict__ W0, const short* __restrict__ W1, const short* __restrict__ W2,
    const float* __restrict__ bi0, const float* __restrict__ bi1, const float* __restrict__ bi2,
    short* __restrict__ o0, short* __restrict__ o1, short* __restrict__ o2)
{
    __shared__ __align__(16) short sa[2][4096];
    __shared__ __align__(16) short sb[2][4096];
    const int z = blockIdx.z;
    const short* A = z == 0 ? A0 : (z == 1 ? A1 : A2);
    const short* W = z == 0 ? W0 : (z == 1 ? W1 : W2);
    const float* bias = z == 0 ? bi0 : (z == 1 ? bi1 : bi2);
    short* outp = z == 0 ? o0 : (z == 1 ? o1 : o2);

    const int tid = threadIdx.x;
    const int w = tid >> 6, l = tid & 63;
    const int lr = l & 15, lh = l >> 4;
    const int m0 = blockIdx.x * 128, n0 = blockIdx.y * 128;
    const int wr = (w >> 1) * 64, wc = (w & 1) * 64;
    const int aoff = (lr >> 1) * 64 + (lr & 1) * 8 + lh * 16;

    f32x4 acc[4][4] = {};

    stage_tile(sa[0], sb[0], A, W, m0, n0, 0, tid);
    __syncthreads();
    for (int k0 = 0; k0 < 1024; k0 += 64) {
        stage_tile(sa[1], sb[1], A, W, m0, n0, k0 + 32, tid);
        gemm_compute(sa[0], sb[0], wr, wc, aoff, acc);
        __syncthreads();
        if (k0 + 64 < 1024)
            stage_tile(sa[0], sb[0], A, W, m0, n0, k0 + 64, tid);
        gemm_compute(sa[1], sb[1], wr, wc, aoff, acc);
        __syncthreads();
    }

    const float scl = (z == 0) ? 0.125f * LOG2E : 1.0f;
#pragma unroll
    for (int i = 0; i < 4; ++i) {
#pragma unroll
        for (int j = 0; j < 4; ++j) {
#pragma unroll
            for (int r = 0; r < 4; ++r) {
                const int row = m0 + wr + i * 16 + lh * 4 + r;  // b*2048+s
                const int col = n0 + wc + j * 16 + lr;          // h*64+d
                const float v = (acc[i][j][r] + bias[col]) * scl;
                const int b = row >> 11, s = row & 2047;
                const int h = col >> 6, d = col & 63;
                if (z != 2)
                    outp[(((long)(b * 16 + h)) * 2048 + s) * 64 + d] = to_bf16s(v);
                else
                    outp[(((long)(b * 16 + h)) * 64 + d) * 2048 + s] = to_bf16s(v);
            }
        }
    }
}

// output GEMM: f32 epilogue to d_out
__global__ __launch_bounds__(256, 2) void out_gemm(
    const short* __restrict__ A, const short* __restrict__ W,
    const float* __restrict__ bias, float* __restrict__ outp)
{
    __shared__ __align__(16) short sa[2][4096];
    __shared__ __align__(16) short sb[2][4096];
    const int tid = threadIdx.x;
    const int w = tid >> 6, l = tid & 63;
    const int lr = l & 15, lh = l >> 4;
    const int m0 = blockIdx.x * 128, n0 = blockIdx.y * 128;
    const int wr = (w >> 1) * 64, wc = (w & 1) * 64;
    const int aoff = (lr >> 1) * 64 + (lr & 1) * 8 + lh * 16;

    f32x4 acc[4][4] = {};

    stage_tile(sa[0], sb[0], A, W, m0, n0, 0, tid);
    __syncthreads();
    for (int k0 = 0; k0 < 1024; k0 += 64) {
        stage_tile(sa[1], sb[1], A, W, m0, n0, k0 + 32, tid);
        gemm_compute(sa[0], sb[0], wr, wc, aoff, acc);
        __syncthreads();
        if (k0 + 64 < 1024)
            stage_tile(sa[0], sb[0], A, W, m0, n0, k0 + 64, tid);
        gemm_compute(sa[1], sb[1], wr, wc, aoff, acc);
        __syncthreads();
    }

#pragma unroll
    for (int i = 0; i < 4; ++i)
#pragma unroll
        for (int j = 0; j < 4; ++j)
#pragma unroll
            for (int r = 0; r < 4; ++r) {
                const int row = m0 + wr + i * 16 + lh * 4 + r;
                const int col = n0 + wc + j * 16 + lr;
                outp[(long)row * 1024 + col] = acc[i][j][r] + bias[col];
            }
}

// ---------------- flash attention v5 ----------------
// 512 blocks XCD-remapped (4 heads/XCD, K/V L2-resident), 4 waves x 32 q-rows.
// KVBLK=64, dbuf LDS staging (XOR-swizzled), swapped QK^T, in-register P,
// exp2-domain softmax (Q pre-scaled by 0.125*log2e), defer-max THR=8,
// mask row in LDS.

static __device__ __forceinline__ void stage_kv(
    short* ldsKb, short* ldsVb, const short* Kg, const short* Vg,
    int key0, int w, int srow, int schunk)
{
    __builtin_amdgcn_global_load_lds((gas_ptr)(Kg + (long)(key0 + srow) * 64 + schunk * 8),
                                     (las_ptr)(ldsKb + w * 512), 16, 0, 0);
    __builtin_amdgcn_global_load_lds((gas_ptr)(Kg + (long)(key0 + srow + 32) * 64 + schunk * 8),
                                     (las_ptr)(ldsKb + 2048 + w * 512), 16, 0, 0);
    __builtin_amdgcn_global_load_lds((gas_ptr)(Vg + (long)srow * 2048 + key0 + schunk * 8),
                                     (las_ptr)(ldsVb + w * 512), 16, 0, 0);
    __builtin_amdgcn_global_load_lds((gas_ptr)(Vg + (long)(srow + 32) * 2048 + key0 + schunk * 8),
                                     (las_ptr)(ldsVb + 2048 + w * 512), 16, 0, 0);
}

static __device__ __forceinline__ void attn_step(
    const short* __restrict__ Kbuf, const short* __restrict__ Vbuf,
    const float* __restrict__ ldsM, int key0,
    const bf16x8 (&qf)[2][2], int lr, int lh, int sw,
    float (&mreg)[2], float (&lsum)[2], f32x4 (&ao)[2][4])
{
    f32x4 mb[4];
#pragma unroll
    for (int s = 0; s < 4; ++s)
        mb[s] = *reinterpret_cast<const f32x4*>(ldsM + key0 + s * 16 + lh * 4);

    // swapped QK^T: lane holds q=lr, key=s*16+lh*4+r (already in log2 domain)
    f32x4 sc[2][4];
#pragma unroll
    for (int s = 0; s < 4; ++s) {
        const short* kb = Kbuf + (s * 16 + lr) * 64;
        bf16x8 k0 = *reinterpret_cast<const bf16x8*>(kb + (((lh * 16) ^ sw) >> 1));
        bf16x8 k1 = *reinterpret_cast<const bf16x8*>(kb + (((64 + lh * 16) ^ sw) >> 1));
        f32x4 z = {};
        sc[0][s] = __builtin_amdgcn_mfma_f32_16x16x32_bf16(k0, qf[0][0], z, 0, 0, 0);
        sc[0][s] = __builtin_amdgcn_mfma_f32_16x16x32_bf16(k1, qf[0][1], sc[0][s], 0, 0, 0);
        sc[1][s] = __builtin_amdgcn_mfma_f32_16x16x32_bf16(k0, qf[1][0], z, 0, 0, 0);
        sc[1][s] = __builtin_amdgcn_mfma_f32_16x16x32_bf16(k1, qf[1][1], sc[1][s], 0, 0, 0);
    }

    bf16x4 pb[2][4];
#pragma unroll
    for (int j = 0; j < 2; ++j) {
        float t = -1e30f;
#pragma unroll
        for (int s = 0; s < 4; ++s)
#pragma unroll
            for (int r = 0; r < 4; ++r) {
                const float v = sc[j][s][r] + mb[s][r];
                sc[j][s][r] = v;
                t = fmaxf(t, v);
            }
        t = fmaxf(t, __shfl_xor(t, 16));
        t = fmaxf(t, __shfl_xor(t, 32));
        // defer-max: only rescale when max grew by > 8 (P bounded by 2^8)
        if (__any(t > mreg[j] + 8.0f)) {
            const float mn = fmaxf(mreg[j], t);
            const float sf = EXP2(mreg[j] - mn);
            lsum[j] *= sf;
#pragma unroll
            for (int d4 = 0; d4 < 4; ++d4) ao[j][d4] *= sf;
            mreg[j] = mn;
        }
        float ps = 0.f;
#pragma unroll
        for (int s = 0; s < 4; ++s) {
            const float p0 = EXP2(sc[j][s][0] - mreg[j]);
            const float p1 = EXP2(sc[j][s][1] - mreg[j]);
            const float p2 = EXP2(sc[j][s][2] - mreg[j]);
            const float p3 = EXP2(sc[j][s][3] - mreg[j]);
            ps += (p0 + p1) + (p2 + p3);
            pb[j][s] = pack4(p0, p1, p2, p3);
        }
        ps += __shfl_xor(ps, 16);
        ps += __shfl_xor(ps, 32);
        lsum[j] += ps;
    }

    // PV: ao[j][d4] += V^T-subtile(d4,s) . P(j,s)
#pragma unroll
    for (int s = 0; s < 4; ++s) {
#pragma unroll
        for (int d4 = 0; d4 < 4; ++d4) {
            const short* vb = Vbuf + (d4 * 16 + lr) * 64;
            bf16x4 vf = *reinterpret_cast<const bf16x4*>(vb + (((s * 32 + lh * 8) ^ sw) >> 1));
            ao[0][d4] = mfma16(vf, pb[0][s], ao[0][d4]);
            ao[1][d4] = mfma16(vf, pb[1][s], ao[1][d4]);
        }
    }
}

__global__ __launch_bounds__(256, 2) void attn_kernel(
    const short* __restrict__ Q, const short* __restrict__ Kmat,
    const short* __restrict__ Vt, const float* __restrict__ maskf,
    short* __restrict__ X)
{
    __shared__ __align__(16) short ldsK[2][4096];
    __shared__ __align__(16) short ldsV[2][4096];
    __shared__ __align__(16) float ldsM[2048];

    const int id = blockIdx.x;
    const int slot = id >> 3;
    const int bh = (id & 7) * 4 + (slot >> 4);   // XCD (id&7) serves heads 4x..4x+3
    const int q0 = (slot & 15) * 128;
    const int b = bh >> 4, h = bh & 15;
    const int w = threadIdx.x >> 6, l = threadIdx.x & 63;
    const int lr = l & 15, lh = l >> 4;
    const int sw = (lr & 7) << 4;                // read-side XOR swizzle (bytes)

    const int srow = w * 8 + (l >> 3);
    const int schunk = (l & 7) ^ (srow & 7);

    const short* Kg = Kmat + (long)bh * 2048 * 64;
    const short* Vg = Vt + (long)bh * 64 * 2048;

    // stage mask row (2048 floats) once
#pragma unroll
    for (int rnd = 0; rnd < 2; ++rnd) {
        const int t = rnd * 256 + threadIdx.x;
        __builtin_amdgcn_global_load_lds((gas_ptr)(maskf + (long)b * 2048 + t * 4),
                                         (las_ptr)(ldsM + t * 4), 16, 0, 0);
    }

    // Q B-frags (Q pre-scaled by 0.125*log2e at projection)
    const short* Qp = Q + ((long)bh * 2048 + q0 + w * 32 + lr) * 64 + lh * 8;
    bf16x8 qf[2][2];
    qf[0][0] = *reinterpret_cast<const bf16x8*>(Qp);
    qf[0][1] = *reinterpret_cast<const bf16x8*>(Qp + 32);
    qf[1][0] = *reinterpret_cast<const bf16x8*>(Qp + 16 * 64);
    qf[1][1] = *reinterpret_cast<const bf16x8*>(Qp + 16 * 64 + 32);

    float mreg[2] = {-1e30f, -1e30f}, lsum[2] = {0.f, 0.f};
    f32x4 ao[2][4] = {};

    stage_kv(ldsK[0], ldsV[0], Kg, Vg, 0, w, srow, schunk);
    __syncthreads();

    for (int tt = 0; tt < 16; ++tt) {
        const int key0 = tt * 128;
        stage_kv(ldsK[1], ldsV[1], Kg, Vg, key0 + 64, w, srow, schunk);
        attn_step(ldsK[0], ldsV[0], ldsM, key0, qf, lr, lh, sw, mreg, lsum, ao);
        __syncthreads();
        if (tt < 15)
            stage_kv(ldsK[0], ldsV[0], Kg, Vg, key0 + 128, w, srow, schunk);
        attn_step(ldsK[1], ldsV[1], ldsM, key0 + 64, qf, lr, lh, sw, mreg, lsum, ao);
        __syncthreads();
    }

    // lane holds O^T[d = d4*16 + lh*4 + r][q = lr] per q-subtile j
#pragma unroll
    for (int j = 0; j < 2; ++j) {
        const float inv = 1.0f / fmaxf(lsum[j], 1e-30f);
        const int s = q0 + w * 32 + j * 16 + lr;
        short* Xp = X + ((long)b * 2048 + s) * 1024 + h * 64 + lh * 4;
#pragma unroll
        for (int d4 = 0; d4 < 4; ++d4) {
            short4 o;
            o.x = to_bf16s(ao[j][d4][0] * inv);
            o.y = to_bf16s(ao[j][d4][1] * inv);
            o.z = to_bf16s(ao[j][d4][2] * inv);
            o.w = to_bf16s(ao[j][d4][3] * inv);
            *reinterpret_cast<short4*>(Xp + d4 * 16) = o;
        }
    }
}

// ---------------- launch ----------------
extern "C" void kernel_launch(void* const* d_in, const int* in_sizes, int n_in,
                              void* d_out, int out_size, void* d_ws, size_t ws_size,
                              hipStream_t stream) {
    const float* query = (const float*)d_in[0];
    const float* key_  = (const float*)d_in[1];
    const float* value = (const float*)d_in[2];
    const int*   mask  = (const int*)d_in[3];
    const float* w_q = (const float*)d_in[4];
    const float* b_q = (const float*)d_in[5];
    const float* w_k = (const float*)d_in[6];
    const float* b_k = (const float*)d_in[7];
    const float* w_v = (const float*)d_in[8];
    const float* b_v = (const float*)d_in[9];
    const float* w_o = (const float*)d_in[10];
    const float* b_o = (const float*)d_in[11];

    const long SEQ = 4194304;  // 4096*1024 elements
    const long WSZ = 1048576;  // 1024*1024
    short* ws = (short*)d_ws;
    short* cq = ws;
    short* ck = cq + SEQ;
    short* cv = ck + SEQ;
    short* wq = cv + SEQ;
    short* wk = wq + WSZ;
    short* wv = wk + WSZ;
    short* wo = wv + WSZ;
    short* Qb = wo + WSZ;      // (B,H,S,64), pre-scaled by 0.125*log2e
    short* Kb = Qb + SEQ;
    short* Vt = Kb + SEQ;      // (B,H,64,S)
    short* Xb = cq;            // reuse: cq dead after projections
    float* mkf = (float*)cv;   // reuse: cv dead after projections

    cvt3_kernel<<<12288, 256, 0, stream>>>(query, key_, value, cq, ck, cv);
    cvt4_kernel<<<4096, 256, 0, stream>>>(w_q, w_k, w_v, w_o, wq, wk, wv, wo);

    dim3 blk(256);
    proj_gemm<<<dim3(32, 8, 3), blk, 0, stream>>>(cq, ck, cv, wq, wk, wv,
                                                  b_q, b_k, b_v, Qb, Kb, Vt);

    maskf_kernel<<<16, 256, 0, stream>>>(mask, mkf);  // after proj (cv reuse)

    attn_kernel<<<512, blk, 0, stream>>>(Qb, Kb, Vt, mkf, Xb);

    out_gemm<<<dim3(32, 8), blk, 0, stream>>>(Xb, wo, b_o, (float*)d_out);
}

// Round 6
// 146.797 us; speedup vs baseline: 3.2553x; 1.0084x over previous
//
#include <hip/hip_runtime.h>
#include <hip/hip_bf16.h>

// MHA: B=2, S=2048, N_FEAT=1024, H=16, D=64
// r6: attn with phi-permuted keys -> PV via full 16x16x32 MFMA, in-register P,
//     mask bias as MFMA C-init; out_gemm re-tiled 128x64 (2 blocks/CU).

typedef float f32x4 __attribute__((ext_vector_type(4)));
typedef short bf16x8 __attribute__((ext_vector_type(8)));

typedef const __attribute__((address_space(1))) void* gas_ptr;
typedef __attribute__((address_space(3))) void* las_ptr;

#if __has_builtin(__builtin_amdgcn_exp2f)
#define EXP2(x) __builtin_amdgcn_exp2f(x)
#else
#define EXP2(x) exp2f(x)
#endif
#define LOG2E 1.4426950408889634f

static __device__ __forceinline__ short to_bf16s(float f) {
    __hip_bfloat16 h = __float2bfloat16(f);
    return __builtin_bit_cast(short, h);
}
static __device__ __forceinline__ unsigned pack_bf16(float a, float b) {
    unsigned lo = (unsigned short)__builtin_bit_cast(short, __float2bfloat16(a));
    unsigned hi = (unsigned short)__builtin_bit_cast(short, __float2bfloat16(b));
    return lo | (hi << 16);
}
static __device__ __forceinline__ bf16x8 pack8(const float* p) {
    unsigned d0 = pack_bf16(p[0], p[1]);
    unsigned d1 = pack_bf16(p[2], p[3]);
    unsigned d2 = pack_bf16(p[4], p[5]);
    unsigned d3 = pack_bf16(p[6], p[7]);
    unsigned u4[4] = {d0, d1, d2, d3};
    return __builtin_bit_cast(bf16x8, u4);
}

// ---------------- conversions ----------------
__global__ void cvt3_kernel(const float* __restrict__ s0, const float* __restrict__ s1,
                            const float* __restrict__ s2, short* __restrict__ d0,
                            short* __restrict__ d1, short* __restrict__ d2) {
    const int g = blockIdx.x;
    const int sel = g >> 12;
    const int i = (g & 4095) * 256 + threadIdx.x;
    const float* s = sel == 0 ? s0 : (sel == 1 ? s1 : s2);
    short* d = sel == 0 ? d0 : (sel == 1 ? d1 : d2);
    float4 v = reinterpret_cast<const float4*>(s)[i];
    short4 o;
    o.x = to_bf16s(v.x); o.y = to_bf16s(v.y); o.z = to_bf16s(v.z); o.w = to_bf16s(v.w);
    reinterpret_cast<short4*>(d)[i] = o;
}
__global__ void cvt4_kernel(const float* __restrict__ s0, const float* __restrict__ s1,
                            const float* __restrict__ s2, const float* __restrict__ s3,
                            short* __restrict__ d0, short* __restrict__ d1,
                            short* __restrict__ d2, short* __restrict__ d3) {
    const int g = blockIdx.x;
    const int sel = g >> 10;
    const int i = (g & 1023) * 256 + threadIdx.x;
    const float* s = sel == 0 ? s0 : (sel == 1 ? s1 : (sel == 2 ? s2 : s3));
    short* d = sel == 0 ? d0 : (sel == 1 ? d1 : (sel == 2 ? d2 : d3));
    float4 v = reinterpret_cast<const float4*>(s)[i];
    short4 o;
    o.x = to_bf16s(v.x); o.y = to_bf16s(v.y); o.z = to_bf16s(v.z); o.w = to_bf16s(v.w);
    reinterpret_cast<short4*>(d)[i] = o;
}

// mask -> additive log2-domain bias, PHI-PERMUTED within each 32-key chunk
// (must match K-row staging permutation in attn).
__global__ void maskf_kernel(const int* __restrict__ mask, float* __restrict__ mf) {
    const int i = blockIdx.x * 256 + threadIdx.x;
    const int p = i & 31;
    const int phi = 8 * ((p >> 2) & 3) + 4 * (p >> 4) + (p & 3);
    mf[i] = mask[(i & ~31) | phi] ? (-10000.0f * LOG2E) : 0.0f;
}

// ---------------- GEMM core: dbuf 2-phase, rowpair-interleaved LDS ----------------
static __device__ __forceinline__ void stage_tile(
    short* sa, short* sb, const short* A, const short* W,
    int m0, int n0, int k0, int tid)
{
#pragma unroll
    for (int rnd = 0; rnd < 2; ++rnd) {
        const int t = rnd * 256 + tid;
        const int c2 = t & 7;
        const int row = 2 * (t >> 3) + (c2 & 1);
        const int col = (c2 >> 1) * 8;
        __builtin_amdgcn_global_load_lds((gas_ptr)(A + (long)(m0 + row) * 1024 + k0 + col),
                                         (las_ptr)(sa + t * 8), 16, 0, 0);
        __builtin_amdgcn_global_load_lds((gas_ptr)(W + (long)(n0 + row) * 1024 + k0 + col),
                                         (las_ptr)(sb + t * 8), 16, 0, 0);
    }
}

static __device__ __forceinline__ void gemm_compute(
    const short* sa, const short* sb, int wr, int wc, int aoff, f32x4 (&acc)[4][4])
{
    bf16x8 af[4], bfr[4];
#pragma unroll
    for (int i = 0; i < 4; ++i)
        af[i] = *reinterpret_cast<const bf16x8*>(sa + (wr + i * 16) * 32 + aoff);
#pragma unroll
    for (int j = 0; j < 4; ++j)
        bfr[j] = *reinterpret_cast<const bf16x8*>(sb + (wc + j * 16) * 32 + aoff);
#pragma unroll
    for (int i = 0; i < 4; ++i)
#pragma unroll
        for (int j = 0; j < 4; ++j)
            acc[i][j] = __builtin_amdgcn_mfma_f32_16x16x32_bf16(af[i], bfr[j], acc[i][j], 0, 0, 0);
}

// fused Q/K/V projection: blockIdx.z selects; Q scaled by 0.125*log2e
__global__ __launch_bounds__(256, 3) void proj_gemm(
    const short* __restrict__ A0, const short* __restrict__ A1, const short* __restrict__ A2,
    const short* __restrict__ W0, const short* __restrict__ W1, const short* __restrict__ W2,
    const float* __restrict__ bi0, const float* __restrict__ bi1, const float* __restrict__ bi2,
    short* __restrict__ o0, short* __restrict__ o1, short* __restrict__ o2)
{
    __shared__ __align__(16) short sa[2][4096];
    __shared__ __align__(16) short sb[2][4096];
    const int z = blockIdx.z;
    const short* A = z == 0 ? A0 : (z == 1 ? A1 : A2);
    const short* W = z == 0 ? W0 : (z == 1 ? W1 : W2);
    const float* bias = z == 0 ? bi0 : (z == 1 ? bi1 : bi2);
    short* outp = z == 0 ? o0 : (z == 1 ? o1 : o2);

    const int tid = threadIdx.x;
    const int w = tid >> 6, l = tid & 63;
    const int lr = l & 15, lh = l >> 4;
    const int m0 = blockIdx.x * 128, n0 = blockIdx.y * 128;
    const int wr = (w >> 1) * 64, wc = (w & 1) * 64;
    const int aoff = (lr >> 1) * 64 + (lr & 1) * 8 + lh * 16;

    f32x4 acc[4][4] = {};

    stage_tile(sa[0], sb[0], A, W, m0, n0, 0, tid);
    __syncthreads();
    for (int k0 = 0; k0 < 1024; k0 += 64) {
        stage_tile(sa[1], sb[1], A, W, m0, n0, k0 + 32, tid);
        gemm_compute(sa[0], sb[0], wr, wc, aoff, acc);
        __syncthreads();
        if (k0 + 64 < 1024)
            stage_tile(sa[0], sb[0], A, W, m0, n0, k0 + 64, tid);
        gemm_compute(sa[1], sb[1], wr, wc, aoff, acc);
        __syncthreads();
    }

    const float scl = (z == 0) ? 0.125f * LOG2E : 1.0f;
#pragma unroll
    for (int i = 0; i < 4; ++i) {
#pragma unroll
        for (int j = 0; j < 4; ++j) {
#pragma unroll
            for (int r = 0; r < 4; ++r) {
                const int row = m0 + wr + i * 16 + lh * 4 + r;  // b*2048+s
                const int col = n0 + wc + j * 16 + lr;          // h*64+d
                const float v = (acc[i][j][r] + bias[col]) * scl;
                const int b = row >> 11, s = row & 2047;
                const int h = col >> 6, d = col & 63;
                if (z != 2)
                    outp[(((long)(b * 16 + h)) * 2048 + s) * 64 + d] = to_bf16s(v);
                else
                    outp[(((long)(b * 16 + h)) * 64 + d) * 2048 + s] = to_bf16s(v);
            }
        }
    }
}

// output GEMM: 128x64 tile -> 512 blocks (2/CU), f32 epilogue
__global__ __launch_bounds__(256, 2) void out_gemm(
    const short* __restrict__ A, const short* __restrict__ W,
    const float* __restrict__ bias, float* __restrict__ outp)
{
    __shared__ __align__(16) short sa[2][4096];
    __shared__ __align__(16) short sb[2][2048];
    const int tid = threadIdx.x;
    const int w = tid >> 6, l = tid & 63;
    const int lr = l & 15, lh = l >> 4;
    const int m0 = blockIdx.x * 128, n0 = blockIdx.y * 64;
    const int wr = (w >> 1) * 64, wc = (w & 1) * 32;
    const int aoff = (lr >> 1) * 64 + (lr & 1) * 8 + lh * 16;

    f32x4 acc[4][2] = {};

    const int c2 = tid & 7;
    const int brow = 2 * (tid >> 3) + (c2 & 1);
    const int bcol = (c2 >> 1) * 8;

    auto stage = [&](short* pa, short* pb, int k0) {
#pragma unroll
        for (int rnd = 0; rnd < 2; ++rnd) {
            const int t = rnd * 256 + tid;
            const int cc = t & 7;
            const int row = 2 * (t >> 3) + (cc & 1);
            const int col = (cc >> 1) * 8;
            __builtin_amdgcn_global_load_lds((gas_ptr)(A + (long)(m0 + row) * 1024 + k0 + col),
                                             (las_ptr)(pa + t * 8), 16, 0, 0);
        }
        __builtin_amdgcn_global_load_lds((gas_ptr)(W + (long)(n0 + brow) * 1024 + k0 + bcol),
                                         (las_ptr)(pb + tid * 8), 16, 0, 0);
    };
    auto compute = [&](const short* pa, const short* pb) {
        bf16x8 af[4], bfr[2];
#pragma unroll
        for (int i = 0; i < 4; ++i)
            af[i] = *reinterpret_cast<const bf16x8*>(pa + (wr + i * 16) * 32 + aoff);
#pragma unroll
        for (int j = 0; j < 2; ++j)
            bfr[j] = *reinterpret_cast<const bf16x8*>(pb + (wc + j * 16) * 32 + aoff);
#pragma unroll
        for (int i = 0; i < 4; ++i)
#pragma unroll
            for (int j = 0; j < 2; ++j)
                acc[i][j] = __builtin_amdgcn_mfma_f32_16x16x32_bf16(af[i], bfr[j], acc[i][j], 0, 0, 0);
    };

    stage(sa[0], sb[0], 0);
    __syncthreads();
    for (int k0 = 0; k0 < 1024; k0 += 64) {
        stage(sa[1], sb[1], k0 + 32);
        compute(sa[0], sb[0]);
        __syncthreads();
        if (k0 + 64 < 1024)
            stage(sa[0], sb[0], k0 + 64);
        compute(sa[1], sb[1]);
        __syncthreads();
    }

#pragma unroll
    for (int i = 0; i < 4; ++i)
#pragma unroll
        for (int j = 0; j < 2; ++j)
#pragma unroll
            for (int r = 0; r < 4; ++r) {
                const int row = m0 + wr + i * 16 + lh * 4 + r;
                const int col = n0 + wc + j * 16 + lr;
                outp[(long)row * 1024 + col] = acc[i][j][r] + bias[col];
            }
}

// ---------------- flash attention v6 ----------------
// 512 blocks XCD-remapped; 4 waves x 32 q-rows. KVBLK=64 (2 chunks of 32 keys).
// K rows staged PHI-PERMUTED per 32-chunk: LDS row p holds global key phi(p),
// phi(p) = 8*((p>>2)&3) + 4*(p>>4) + (p&3). Then the swapped-QK^T C-layout,
// packed in-lane [tile2c r0..3 | tile2c+1 r0..3], IS the 16x16x32 B-frag over
// LINEAR keys -> PV uses full-K MFMA, V stays linear, zero cross-lane ops.
// Mask bias (phi-permuted in maskf_kernel) enters as the QK^T MFMA C-init.

static __device__ __forceinline__ void stage_kv(
    short* ldsKb, short* ldsVb, const short* Kg, const short* Vg,
    int key0, int w, int srow, int prow, int schunk)
{
    // K: LDS row srow (+32) <- global key key0 + phi(srow) (+32)
    __builtin_amdgcn_global_load_lds((gas_ptr)(Kg + (long)(key0 + prow) * 64 + schunk * 8),
                                     (las_ptr)(ldsKb + w * 512), 16, 0, 0);
    __builtin_amdgcn_global_load_lds((gas_ptr)(Kg + (long)(key0 + 32 + prow) * 64 + schunk * 8),
                                     (las_ptr)(ldsKb + 2048 + w * 512), 16, 0, 0);
    // V^T: rows = d, keys linear
    __builtin_amdgcn_global_load_lds((gas_ptr)(Vg + (long)srow * 2048 + key0 + schunk * 8),
                                     (las_ptr)(ldsVb + w * 512), 16, 0, 0);
    __builtin_amdgcn_global_load_lds((gas_ptr)(Vg + (long)(srow + 32) * 2048 + key0 + schunk * 8),
                                     (las_ptr)(ldsVb + 2048 + w * 512), 16, 0, 0);
}

static __device__ __forceinline__ void attn_step(
    const short* __restrict__ Kbuf, const short* __restrict__ Vbuf,
    const float* __restrict__ ldsM, int key0,
    const bf16x8 (&qf)[2][2], int lr, int lh, int sw,
    float (&mreg)[2], float (&lsum)[2], f32x4 (&ao)[2][4])
{
    // mask bias (log2-domain, phi-permuted) as MFMA C-init
    f32x4 mb[4];
#pragma unroll
    for (int s = 0; s < 4; ++s)
        mb[s] = *reinterpret_cast<const f32x4*>(ldsM + key0 + s * 16 + lh * 4);

    // swapped QK^T: lane holds q=lr, physical key-slot = 16s + 4lh + r
    f32x4 sc[2][4];
#pragma unroll
    for (int s = 0; s < 4; ++s) {
        const short* kb = Kbuf + (s * 16 + lr) * 64;
        bf16x8 k0 = *reinterpret_cast<const bf16x8*>(kb + (((lh * 16) ^ sw) >> 1));
        bf16x8 k1 = *reinterpret_cast<const bf16x8*>(kb + (((64 + lh * 16) ^ sw) >> 1));
        sc[0][s] = __builtin_amdgcn_mfma_f32_16x16x32_bf16(k0, qf[0][0], mb[s], 0, 0, 0);
        sc[0][s] = __builtin_amdgcn_mfma_f32_16x16x32_bf16(k1, qf[0][1], sc[0][s], 0, 0, 0);
        sc[1][s] = __builtin_amdgcn_mfma_f32_16x16x32_bf16(k0, qf[1][0], mb[s], 0, 0, 0);
        sc[1][s] = __builtin_amdgcn_mfma_f32_16x16x32_bf16(k1, qf[1][1], sc[1][s], 0, 0, 0);
    }

    bf16x8 pb[2][2];
#pragma unroll
    for (int j = 0; j < 2; ++j) {
        float m0 = fmaxf(fmaxf(fmaxf(sc[j][0][0], sc[j][0][1]), sc[j][0][2]), sc[j][0][3]);
        float m1 = fmaxf(fmaxf(fmaxf(sc[j][1][0], sc[j][1][1]), sc[j][1][2]), sc[j][1][3]);
        float m2 = fmaxf(fmaxf(fmaxf(sc[j][2][0], sc[j][2][1]), sc[j][2][2]), sc[j][2][3]);
        float m3 = fmaxf(fmaxf(fmaxf(sc[j][3][0], sc[j][3][1]), sc[j][3][2]), sc[j][3][3]);
        float t = fmaxf(fmaxf(m0, m1), fmaxf(m2, m3));
        t = fmaxf(t, __shfl_xor(t, 16));
        t = fmaxf(t, __shfl_xor(t, 32));
        // defer-max: rescale only when max grew by > 8 (P bounded by 2^8)
        if (__any(t > mreg[j] + 8.0f)) {
            const float mn = fmaxf(mreg[j], t);
            const float sf = EXP2(mreg[j] - mn);
            lsum[j] *= sf;
#pragma unroll
            for (int d4 = 0; d4 < 4; ++d4) ao[j][d4] *= sf;
            mreg[j] = mn;
        }
        float p[16], ps = 0.f;
#pragma unroll
        for (int s = 0; s < 4; ++s) {
#pragma unroll
            for (int r = 0; r < 4; ++r) {
                const float e = EXP2(sc[j][s][r] - mreg[j]);
                p[s * 4 + r] = e;
                ps += e;
            }
        }
        ps += __shfl_xor(ps, 16);
        ps += __shfl_xor(ps, 32);
        lsum[j] += ps;
        pb[j][0] = pack8(p);       // chunk 0: tiles s=0,1
        pb[j][1] = pack8(p + 8);   // chunk 1: tiles s=2,3
    }

    // PV via 16x16x32: A = V^T rows (linear keys), B = pb (in-register)
#pragma unroll
    for (int c = 0; c < 2; ++c) {
#pragma unroll
        for (int d4 = 0; d4 < 4; ++d4) {
            const short* vb = Vbuf + (d4 * 16 + lr) * 64;
            bf16x8 vf = *reinterpret_cast<const bf16x8*>(vb + (((c * 64 + lh * 16) ^ sw) >> 1));
            ao[0][d4] = __builtin_amdgcn_mfma_f32_16x16x32_bf16(vf, pb[0][c], ao[0][d4], 0, 0, 0);
            ao[1][d4] = __builtin_amdgcn_mfma_f32_16x16x32_bf16(vf, pb[1][c], ao[1][d4], 0, 0, 0);
        }
    }
}

__global__ __launch_bounds__(256, 2) void attn_kernel(
    const short* __restrict__ Q, const short* __restrict__ Kmat,
    const short* __restrict__ Vt, const float* __restrict__ maskf,
    short* __restrict__ X)
{
    __shared__ __align__(16) short ldsK[2][4096];
    __shared__ __align__(16) short ldsV[2][4096];
    __shared__ __align__(16) float ldsM[2048];

    const int id = blockIdx.x;
    const int slot = id >> 3;
    const int bh = (id & 7) * 4 + (slot >> 4);   // XCD (id&7) serves heads 4x..4x+3
    const int q0 = (slot & 15) * 128;
    const int b = bh >> 4, h = bh & 15;
    const int w = threadIdx.x >> 6, l = threadIdx.x & 63;
    const int lr = l & 15, lh = l >> 4;
    const int sw = (lr & 7) << 4;                // read-side XOR swizzle (bytes)

    const int srow = w * 8 + (l >> 3);           // 0..31
    const int schunk = (l & 7) ^ (srow & 7);
    const int prow = 8 * ((srow >> 2) & 3) + 4 * (srow >> 4) + (srow & 3);  // phi

    const short* Kg = Kmat + (long)bh * 2048 * 64;
    const short* Vg = Vt + (long)bh * 64 * 2048;

    // stage mask row (2048 floats, already phi-permuted) once
#pragma unroll
    for (int rnd = 0; rnd < 2; ++rnd) {
        const int t = rnd * 256 + threadIdx.x;
        __builtin_amdgcn_global_load_lds((gas_ptr)(maskf + (long)b * 2048 + t * 4),
                                         (las_ptr)(ldsM + t * 4), 16, 0, 0);
    }

    // Q B-frags (Q pre-scaled by 0.125*log2e at projection)
    const short* Qp = Q + ((long)bh * 2048 + q0 + w * 32 + lr) * 64 + lh * 8;
    bf16x8 qf[2][2];
    qf[0][0] = *reinterpret_cast<const bf16x8*>(Qp);
    qf[0][1] = *reinterpret_cast<const bf16x8*>(Qp + 32);
    qf[1][0] = *reinterpret_cast<const bf16x8*>(Qp + 16 * 64);
    qf[1][1] = *reinterpret_cast<const bf16x8*>(Qp + 16 * 64 + 32);

    float mreg[2] = {-1e30f, -1e30f}, lsum[2] = {0.f, 0.f};
    f32x4 ao[2][4] = {};

    stage_kv(ldsK[0], ldsV[0], Kg, Vg, 0, w, srow, prow, schunk);
    __syncthreads();

    for (int tt = 0; tt < 16; ++tt) {
        const int key0 = tt * 128;
        stage_kv(ldsK[1], ldsV[1], Kg, Vg, key0 + 64, w, srow, prow, schunk);
        attn_step(ldsK[0], ldsV[0], ldsM, key0, qf, lr, lh, sw, mreg, lsum, ao);
        __syncthreads();
        if (tt < 15)
            stage_kv(ldsK[0], ldsV[0], Kg, Vg, key0 + 128, w, srow, prow, schunk);
        attn_step(ldsK[1], ldsV[1], ldsM, key0 + 64, qf, lr, lh, sw, mreg, lsum, ao);
        __syncthreads();
    }

    // lane holds O^T[d = d4*16 + lh*4 + r][q = lr] per q-subtile j
#pragma unroll
    for (int j = 0; j < 2; ++j) {
        const float inv = 1.0f / fmaxf(lsum[j], 1e-30f);
        const int s = q0 + w * 32 + j * 16 + lr;
        short* Xp = X + ((long)b * 2048 + s) * 1024 + h * 64 + lh * 4;
#pragma unroll
        for (int d4 = 0; d4 < 4; ++d4) {
            short4 o;
            o.x = to_bf16s(ao[j][d4][0] * inv);
            o.y = to_bf16s(ao[j][d4][1] * inv);
            o.z = to_bf16s(ao[j][d4][2] * inv);
            o.w = to_bf16s(ao[j][d4][3] * inv);
            *reinterpret_cast<short4*>(Xp + d4 * 16) = o;
        }
    }
}

// ---------------- launch ----------------
extern "C" void kernel_launch(void* const* d_in, const int* in_sizes, int n_in,
                              void* d_out, int out_size, void* d_ws, size_t ws_size,
                              hipStream_t stream) {
    const float* query = (const float*)d_in[0];
    const float* key_  = (const float*)d_in[1];
    const float* value = (const float*)d_in[2];
    const int*   mask  = (const int*)d_in[3];
    const float* w_q = (const float*)d_in[4];
    const float* b_q = (const float*)d_in[5];
    const float* w_k = (const float*)d_in[6];
    const float* b_k = (const float*)d_in[7];
    const float* w_v = (const float*)d_in[8];
    const float* b_v = (const float*)d_in[9];
    const float* w_o = (const float*)d_in[10];
    const float* b_o = (const float*)d_in[11];

    const long SEQ = 4194304;  // 4096*1024 elements
    const long WSZ = 1048576;  // 1024*1024
    short* ws = (short*)d_ws;
    short* cq = ws;
    short* ck = cq + SEQ;
    short* cv = ck + SEQ;
    short* wq = cv + SEQ;
    short* wk = wq + WSZ;
    short* wv = wk + WSZ;
    short* wo = wv + WSZ;
    short* Qb = wo + WSZ;      // (B,H,S,64), pre-scaled by 0.125*log2e
    short* Kb = Qb + SEQ;
    short* Vt = Kb + SEQ;      // (B,H,64,S)
    short* Xb = cq;            // reuse: cq dead after projections
    float* mkf = (float*)cv;   // reuse: cv dead after projections

    cvt3_kernel<<<12288, 256, 0, stream>>>(query, key_, value, cq, ck, cv);
    cvt4_kernel<<<4096, 256, 0, stream>>>(w_q, w_k, w_v, w_o, wq, wk, wv, wo);

    dim3 blk(256);
    proj_gemm<<<dim3(32, 8, 3), blk, 0, stream>>>(cq, ck, cv, wq, wk, wv,
                                                  b_q, b_k, b_v, Qb, Kb, Vt);

    maskf_kernel<<<16, 256, 0, stream>>>(mask, mkf);  // after proj (cv reuse)

    attn_kernel<<<512, blk, 0, stream>>>(Qb, Kb, Vt, mkf, Xb);

    out_gemm<<<dim3(32, 16), blk, 0, stream>>>(Xb, wo, b_o, (float*)d_out);
}

// Round 7
// 142.330 us; speedup vs baseline: 3.3575x; 1.0314x over previous
//
#include <hip/hip_runtime.h>
#include <hip/hip_bf16.h>

// MHA: B=2, S=2048, N_FEAT=1024, H=16, D=64
// r7: attn re-gridded to 1024 blocks (4 waves x 16 q-rows; 4 blocks/CU) and
//     P-pack via v_cvt_pk_bf16_f32. GEMMs unchanged from r6.

typedef float f32x4 __attribute__((ext_vector_type(4)));
typedef short bf16x8 __attribute__((ext_vector_type(8)));

typedef const __attribute__((address_space(1))) void* gas_ptr;
typedef __attribute__((address_space(3))) void* las_ptr;

#if __has_builtin(__builtin_amdgcn_exp2f)
#define EXP2(x) __builtin_amdgcn_exp2f(x)
#else
#define EXP2(x) exp2f(x)
#endif
#define LOG2E 1.4426950408889634f

static __device__ __forceinline__ short to_bf16s(float f) {
    __hip_bfloat16 h = __float2bfloat16(f);
    return __builtin_bit_cast(short, h);
}
// packed f32->bf16 (RNE), one instruction for two values: dst.lo=src0, dst.hi=src1
static __device__ __forceinline__ unsigned cvtpk(float lo, float hi) {
    unsigned r;
    asm("v_cvt_pk_bf16_f32 %0, %1, %2" : "=v"(r) : "v"(lo), "v"(hi));
    return r;
}

// ---------------- conversions ----------------
__global__ void cvt3_kernel(const float* __restrict__ s0, const float* __restrict__ s1,
                            const float* __restrict__ s2, short* __restrict__ d0,
                            short* __restrict__ d1, short* __restrict__ d2) {
    const int g = blockIdx.x;
    const int sel = g >> 12;
    const int i = (g & 4095) * 256 + threadIdx.x;
    const float* s = sel == 0 ? s0 : (sel == 1 ? s1 : s2);
    short* d = sel == 0 ? d0 : (sel == 1 ? d1 : d2);
    float4 v = reinterpret_cast<const float4*>(s)[i];
    short4 o;
    o.x = to_bf16s(v.x); o.y = to_bf16s(v.y); o.z = to_bf16s(v.z); o.w = to_bf16s(v.w);
    reinterpret_cast<short4*>(d)[i] = o;
}
__global__ void cvt4_kernel(const float* __restrict__ s0, const float* __restrict__ s1,
                            const float* __restrict__ s2, const float* __restrict__ s3,
                            short* __restrict__ d0, short* __restrict__ d1,
                            short* __restrict__ d2, short* __restrict__ d3) {
    const int g = blockIdx.x;
    const int sel = g >> 10;
    const int i = (g & 1023) * 256 + threadIdx.x;
    const float* s = sel == 0 ? s0 : (sel == 1 ? s1 : (sel == 2 ? s2 : s3));
    short* d = sel == 0 ? d0 : (sel == 1 ? d1 : (sel == 2 ? d2 : d3));
    float4 v = reinterpret_cast<const float4*>(s)[i];
    short4 o;
    o.x = to_bf16s(v.x); o.y = to_bf16s(v.y); o.z = to_bf16s(v.z); o.w = to_bf16s(v.w);
    reinterpret_cast<short4*>(d)[i] = o;
}

// mask -> additive log2-domain bias, PHI-PERMUTED within each 32-key chunk
__global__ void maskf_kernel(const int* __restrict__ mask, float* __restrict__ mf) {
    const int i = blockIdx.x * 256 + threadIdx.x;
    const int p = i & 31;
    const int phi = 8 * ((p >> 2) & 3) + 4 * (p >> 4) + (p & 3);
    mf[i] = mask[(i & ~31) | phi] ? (-10000.0f * LOG2E) : 0.0f;
}

// ---------------- GEMM core: dbuf 2-phase, rowpair-interleaved LDS ----------------
static __device__ __forceinline__ void stage_tile(
    short* sa, short* sb, const short* A, const short* W,
    int m0, int n0, int k0, int tid)
{
#pragma unroll
    for (int rnd = 0; rnd < 2; ++rnd) {
        const int t = rnd * 256 + tid;
        const int c2 = t & 7;
        const int row = 2 * (t >> 3) + (c2 & 1);
        const int col = (c2 >> 1) * 8;
        __builtin_amdgcn_global_load_lds((gas_ptr)(A + (long)(m0 + row) * 1024 + k0 + col),
                                         (las_ptr)(sa + t * 8), 16, 0, 0);
        __builtin_amdgcn_global_load_lds((gas_ptr)(W + (long)(n0 + row) * 1024 + k0 + col),
                                         (las_ptr)(sb + t * 8), 16, 0, 0);
    }
}

static __device__ __forceinline__ void gemm_compute(
    const short* sa, const short* sb, int wr, int wc, int aoff, f32x4 (&acc)[4][4])
{
    bf16x8 af[4], bfr[4];
#pragma unroll
    for (int i = 0; i < 4; ++i)
        af[i] = *reinterpret_cast<const bf16x8*>(sa + (wr + i * 16) * 32 + aoff);
#pragma unroll
    for (int j = 0; j < 4; ++j)
        bfr[j] = *reinterpret_cast<const bf16x8*>(sb + (wc + j * 16) * 32 + aoff);
#pragma unroll
    for (int i = 0; i < 4; ++i)
#pragma unroll
        for (int j = 0; j < 4; ++j)
            acc[i][j] = __builtin_amdgcn_mfma_f32_16x16x32_bf16(af[i], bfr[j], acc[i][j], 0, 0, 0);
}

// fused Q/K/V projection: blockIdx.z selects; Q scaled by 0.125*log2e
__global__ __launch_bounds__(256, 3) void proj_gemm(
    const short* __restrict__ A0, const short* __restrict__ A1, const short* __restrict__ A2,
    const short* __restrict__ W0, const short* __restrict__ W1, const short* __restrict__ W2,
    const float* __restrict__ bi0, const float* __restrict__ bi1, const float* __restrict__ bi2,
    short* __restrict__ o0, short* __restrict__ o1, short* __restrict__ o2)
{
    __shared__ __align__(16) short sa[2][4096];
    __shared__ __align__(16) short sb[2][4096];
    const int z = blockIdx.z;
    const short* A = z == 0 ? A0 : (z == 1 ? A1 : A2);
    const short* W = z == 0 ? W0 : (z == 1 ? W1 : W2);
    const float* bias = z == 0 ? bi0 : (z == 1 ? bi1 : bi2);
    short* outp = z == 0 ? o0 : (z == 1 ? o1 : o2);

    const int tid = threadIdx.x;
    const int w = tid >> 6, l = tid & 63;
    const int lr = l & 15, lh = l >> 4;
    const int m0 = blockIdx.x * 128, n0 = blockIdx.y * 128;
    const int wr = (w >> 1) * 64, wc = (w & 1) * 64;
    const int aoff = (lr >> 1) * 64 + (lr & 1) * 8 + lh * 16;

    f32x4 acc[4][4] = {};

    stage_tile(sa[0], sb[0], A, W, m0, n0, 0, tid);
    __syncthreads();
    for (int k0 = 0; k0 < 1024; k0 += 64) {
        stage_tile(sa[1], sb[1], A, W, m0, n0, k0 + 32, tid);
        gemm_compute(sa[0], sb[0], wr, wc, aoff, acc);
        __syncthreads();
        if (k0 + 64 < 1024)
            stage_tile(sa[0], sb[0], A, W, m0, n0, k0 + 64, tid);
        gemm_compute(sa[1], sb[1], wr, wc, aoff, acc);
        __syncthreads();
    }

    const float scl = (z == 0) ? 0.125f * LOG2E : 1.0f;
#pragma unroll
    for (int i = 0; i < 4; ++i) {
#pragma unroll
        for (int j = 0; j < 4; ++j) {
#pragma unroll
            for (int r = 0; r < 4; ++r) {
                const int row = m0 + wr + i * 16 + lh * 4 + r;  // b*2048+s
                const int col = n0 + wc + j * 16 + lr;          // h*64+d
                const float v = (acc[i][j][r] + bias[col]) * scl;
                const int b = row >> 11, s = row & 2047;
                const int h = col >> 6, d = col & 63;
                if (z != 2)
                    outp[(((long)(b * 16 + h)) * 2048 + s) * 64 + d] = to_bf16s(v);
                else
                    outp[(((long)(b * 16 + h)) * 64 + d) * 2048 + s] = to_bf16s(v);
            }
        }
    }
}

// output GEMM: 128x64 tile -> 512 blocks (2/CU), f32 epilogue
__global__ __launch_bounds__(256, 2) void out_gemm(
    const short* __restrict__ A, const short* __restrict__ W,
    const float* __restrict__ bias, float* __restrict__ outp)
{
    __shared__ __align__(16) short sa[2][4096];
    __shared__ __align__(16) short sb[2][2048];
    const int tid = threadIdx.x;
    const int w = tid >> 6, l = tid & 63;
    const int lr = l & 15, lh = l >> 4;
    const int m0 = blockIdx.x * 128, n0 = blockIdx.y * 64;
    const int wr = (w >> 1) * 64, wc = (w & 1) * 32;
    const int aoff = (lr >> 1) * 64 + (lr & 1) * 8 + lh * 16;

    f32x4 acc[4][2] = {};

    const int c2 = tid & 7;
    const int brow = 2 * (tid >> 3) + (c2 & 1);
    const int bcol = (c2 >> 1) * 8;

    auto stage = [&](short* pa, short* pb, int k0) {
#pragma unroll
        for (int rnd = 0; rnd < 2; ++rnd) {
            const int t = rnd * 256 + tid;
            const int cc = t & 7;
            const int row = 2 * (t >> 3) + (cc & 1);
            const int col = (cc >> 1) * 8;
            __builtin_amdgcn_global_load_lds((gas_ptr)(A + (long)(m0 + row) * 1024 + k0 + col),
                                             (las_ptr)(pa + t * 8), 16, 0, 0);
        }
        __builtin_amdgcn_global_load_lds((gas_ptr)(W + (long)(n0 + brow) * 1024 + k0 + bcol),
                                         (las_ptr)(pb + tid * 8), 16, 0, 0);
    };
    auto compute = [&](const short* pa, const short* pb) {
        bf16x8 af[4], bfr[2];
#pragma unroll
        for (int i = 0; i < 4; ++i)
            af[i] = *reinterpret_cast<const bf16x8*>(pa + (wr + i * 16) * 32 + aoff);
#pragma unroll
        for (int j = 0; j < 2; ++j)
            bfr[j] = *reinterpret_cast<const bf16x8*>(pb + (wc + j * 16) * 32 + aoff);
#pragma unroll
        for (int i = 0; i < 4; ++i)
#pragma unroll
            for (int j = 0; j < 2; ++j)
                acc[i][j] = __builtin_amdgcn_mfma_f32_16x16x32_bf16(af[i], bfr[j], acc[i][j], 0, 0, 0);
    };

    stage(sa[0], sb[0], 0);
    __syncthreads();
    for (int k0 = 0; k0 < 1024; k0 += 64) {
        stage(sa[1], sb[1], k0 + 32);
        compute(sa[0], sb[0]);
        __syncthreads();
        if (k0 + 64 < 1024)
            stage(sa[0], sb[0], k0 + 64);
        compute(sa[1], sb[1]);
        __syncthreads();
    }

#pragma unroll
    for (int i = 0; i < 4; ++i)
#pragma unroll
        for (int j = 0; j < 2; ++j)
#pragma unroll
            for (int r = 0; r < 4; ++r) {
                const int row = m0 + wr + i * 16 + lh * 4 + r;
                const int col = n0 + wc + j * 16 + lr;
                outp[(long)row * 1024 + col] = acc[i][j][r] + bias[col];
            }
}

// ---------------- flash attention v7 ----------------
// 1024 blocks XCD-remapped (4 heads/XCD); 4 waves x 16 q-rows = 64 q-rows/block;
// 4 blocks/CU (LDS 40960B). KVBLK=64 (2 chunks of 32 keys), dbuf staging.
// K rows phi-permuted per 32-chunk so the swapped-QK^T C-layout packs directly
// into the 16x16x32 B-frag -> PV full-K MFMA, zero cross-lane. Mask bias is
// the QK^T MFMA C-init. P-pack via v_cvt_pk_bf16_f32.

static __device__ __forceinline__ void stage_kv(
    short* ldsKb, short* ldsVb, const short* Kg, const short* Vg,
    int key0, int w, int srow, int prow, int schunk)
{
    __builtin_amdgcn_global_load_lds((gas_ptr)(Kg + (long)(key0 + prow) * 64 + schunk * 8),
                                     (las_ptr)(ldsKb + w * 512), 16, 0, 0);
    __builtin_amdgcn_global_load_lds((gas_ptr)(Kg + (long)(key0 + 32 + prow) * 64 + schunk * 8),
                                     (las_ptr)(ldsKb + 2048 + w * 512), 16, 0, 0);
    __builtin_amdgcn_global_load_lds((gas_ptr)(Vg + (long)srow * 2048 + key0 + schunk * 8),
                                     (las_ptr)(ldsVb + w * 512), 16, 0, 0);
    __builtin_amdgcn_global_load_lds((gas_ptr)(Vg + (long)(srow + 32) * 2048 + key0 + schunk * 8),
                                     (las_ptr)(ldsVb + 2048 + w * 512), 16, 0, 0);
}

static __device__ __forceinline__ void attn_step(
    const short* __restrict__ Kbuf, const short* __restrict__ Vbuf,
    const float* __restrict__ ldsM, int key0,
    const bf16x8 qf0, const bf16x8 qf1, int lr, int lh, int sw,
    float& mreg, float& lsum, f32x4 (&ao)[4])
{
    f32x4 mb[4];
#pragma unroll
    for (int s = 0; s < 4; ++s)
        mb[s] = *reinterpret_cast<const f32x4*>(ldsM + key0 + s * 16 + lh * 4);

    // swapped QK^T: lane holds q=lr, physical key-slot = 16s + 4lh + r
    f32x4 sc[4];
#pragma unroll
    for (int s = 0; s < 4; ++s) {
        const short* kb = Kbuf + (s * 16 + lr) * 64;
        bf16x8 k0 = *reinterpret_cast<const bf16x8*>(kb + (((lh * 16) ^ sw) >> 1));
        bf16x8 k1 = *reinterpret_cast<const bf16x8*>(kb + (((64 + lh * 16) ^ sw) >> 1));
        sc[s] = __builtin_amdgcn_mfma_f32_16x16x32_bf16(k0, qf0, mb[s], 0, 0, 0);
        sc[s] = __builtin_amdgcn_mfma_f32_16x16x32_bf16(k1, qf1, sc[s], 0, 0, 0);
    }

    float m0 = fmaxf(fmaxf(fmaxf(sc[0][0], sc[0][1]), sc[0][2]), sc[0][3]);
    float m1 = fmaxf(fmaxf(fmaxf(sc[1][0], sc[1][1]), sc[1][2]), sc[1][3]);
    float m2 = fmaxf(fmaxf(fmaxf(sc[2][0], sc[2][1]), sc[2][2]), sc[2][3]);
    float m3 = fmaxf(fmaxf(fmaxf(sc[3][0], sc[3][1]), sc[3][2]), sc[3][3]);
    float t = fmaxf(fmaxf(m0, m1), fmaxf(m2, m3));
    t = fmaxf(t, __shfl_xor(t, 16));
    t = fmaxf(t, __shfl_xor(t, 32));
    // defer-max: rescale only when max grew by > 8 (P bounded by 2^8)
    if (__any(t > mreg + 8.0f)) {
        const float mn = fmaxf(mreg, t);
        const float sf = EXP2(mreg - mn);
        lsum *= sf;
#pragma unroll
        for (int d4 = 0; d4 < 4; ++d4) ao[d4] *= sf;
        mreg = mn;
    }
    float p[16], ps = 0.f;
#pragma unroll
    for (int s = 0; s < 4; ++s) {
#pragma unroll
        for (int r = 0; r < 4; ++r) {
            const float e = EXP2(sc[s][r] - mreg);
            p[s * 4 + r] = e;
            ps += e;
        }
    }
    ps += __shfl_xor(ps, 16);
    ps += __shfl_xor(ps, 32);
    lsum += ps;

    // pack P into the two 16x16x32 B-frags (chunk c covers s-tiles 2c, 2c+1)
    unsigned pw[8];
#pragma unroll
    for (int i = 0; i < 8; ++i) pw[i] = cvtpk(p[2 * i], p[2 * i + 1]);
    const bf16x8 pb0 = __builtin_bit_cast(bf16x8, *(ulonglong2*)&pw[0]);
    const bf16x8 pb1 = __builtin_bit_cast(bf16x8, *(ulonglong2*)&pw[4]);

    // PV via 16x16x32: A = V^T rows (linear keys), B = pb (in-register)
#pragma unroll
    for (int c = 0; c < 2; ++c) {
        const bf16x8 pbc = c == 0 ? pb0 : pb1;
#pragma unroll
        for (int d4 = 0; d4 < 4; ++d4) {
            const short* vb = Vbuf + (d4 * 16 + lr) * 64;
            bf16x8 vf = *reinterpret_cast<const bf16x8*>(vb + (((c * 64 + lh * 16) ^ sw) >> 1));
            ao[d4] = __builtin_amdgcn_mfma_f32_16x16x32_bf16(vf, pbc, ao[d4], 0, 0, 0);
        }
    }
}

__global__ __launch_bounds__(256, 4) void attn_kernel(
    const short* __restrict__ Q, const short* __restrict__ Kmat,
    const short* __restrict__ Vt, const float* __restrict__ maskf,
    short* __restrict__ X)
{
    __shared__ __align__(16) short ldsK[2][4096];
    __shared__ __align__(16) short ldsV[2][4096];
    __shared__ __align__(16) float ldsM[2048];

    const int id = blockIdx.x;
    const int slot = id >> 3;
    const int bh = (id & 7) * 4 + (slot >> 5);   // XCD (id&7) serves heads 4x..4x+3
    const int q0 = (slot & 31) * 64;
    const int b = bh >> 4, h = bh & 15;
    const int w = threadIdx.x >> 6, l = threadIdx.x & 63;
    const int lr = l & 15, lh = l >> 4;
    const int sw = (lr & 7) << 4;                // read-side XOR swizzle (bytes)

    const int srow = w * 8 + (l >> 3);           // 0..31
    const int schunk = (l & 7) ^ (srow & 7);
    const int prow = 8 * ((srow >> 2) & 3) + 4 * (srow >> 4) + (srow & 3);  // phi

    const short* Kg = Kmat + (long)bh * 2048 * 64;
    const short* Vg = Vt + (long)bh * 64 * 2048;

    // stage mask row (2048 floats, already phi-permuted) once
#pragma unroll
    for (int rnd = 0; rnd < 2; ++rnd) {
        const int t = rnd * 256 + threadIdx.x;
        __builtin_amdgcn_global_load_lds((gas_ptr)(maskf + (long)b * 2048 + t * 4),
                                         (las_ptr)(ldsM + t * 4), 16, 0, 0);
    }

    // Q B-frag (Q pre-scaled by 0.125*log2e at projection): wave owns 16 q-rows
    const short* Qp = Q + ((long)bh * 2048 + q0 + w * 16 + lr) * 64 + lh * 8;
    const bf16x8 qf0 = *reinterpret_cast<const bf16x8*>(Qp);
    const bf16x8 qf1 = *reinterpret_cast<const bf16x8*>(Qp + 32);

    float mreg = -1e30f, lsum = 0.f;
    f32x4 ao[4] = {};

    stage_kv(ldsK[0], ldsV[0], Kg, Vg, 0, w, srow, prow, schunk);
    __syncthreads();

    for (int tt = 0; tt < 16; ++tt) {
        const int key0 = tt * 128;
        stage_kv(ldsK[1], ldsV[1], Kg, Vg, key0 + 64, w, srow, prow, schunk);
        attn_step(ldsK[0], ldsV[0], ldsM, key0, qf0, qf1, lr, lh, sw, mreg, lsum, ao);
        __syncthreads();
        if (tt < 15)
            stage_kv(ldsK[0], ldsV[0], Kg, Vg, key0 + 128, w, srow, prow, schunk);
        attn_step(ldsK[1], ldsV[1], ldsM, key0 + 64, qf0, qf1, lr, lh, sw, mreg, lsum, ao);
        __syncthreads();
    }

    // lane holds O^T[d = d4*16 + lh*4 + r][q = lr]
    const float inv = 1.0f / fmaxf(lsum, 1e-30f);
    const int s = q0 + w * 16 + lr;
    short* Xp = X + ((long)b * 2048 + s) * 1024 + h * 64 + lh * 4;
#pragma unroll
    for (int d4 = 0; d4 < 4; ++d4) {
        uint2 o;
        o.x = cvtpk(ao[d4][0] * inv, ao[d4][1] * inv);
        o.y = cvtpk(ao[d4][2] * inv, ao[d4][3] * inv);
        *reinterpret_cast<uint2*>(Xp + d4 * 16) = o;
    }
}

// ---------------- launch ----------------
extern "C" void kernel_launch(void* const* d_in, const int* in_sizes, int n_in,
                              void* d_out, int out_size, void* d_ws, size_t ws_size,
                              hipStream_t stream) {
    const float* query = (const float*)d_in[0];
    const float* key_  = (const float*)d_in[1];
    const float* value = (const float*)d_in[2];
    const int*   mask  = (const int*)d_in[3];
    const float* w_q = (const float*)d_in[4];
    const float* b_q = (const float*)d_in[5];
    const float* w_k = (const float*)d_in[6];
    const float* b_k = (const float*)d_in[7];
    const float* w_v = (const float*)d_in[8];
    const float* b_v = (const float*)d_in[9];
    const float* w_o = (const float*)d_in[10];
    const float* b_o = (const float*)d_in[11];

    const long SEQ = 4194304;  // 4096*1024 elements
    const long WSZ = 1048576;  // 1024*1024
    short* ws = (short*)d_ws;
    short* cq = ws;
    short* ck = cq + SEQ;
    short* cv = ck + SEQ;
    short* wq = cv + SEQ;
    short* wk = wq + WSZ;
    short* wv = wk + WSZ;
    short* wo = wv + WSZ;
    short* Qb = wo + WSZ;      // (B,H,S,64), pre-scaled by 0.125*log2e
    short* Kb = Qb + SEQ;
    short* Vt = Kb + SEQ;      // (B,H,64,S)
    short* Xb = cq;            // reuse: cq dead after projections
    float* mkf = (float*)cv;   // reuse: cv dead after projections

    cvt3_kernel<<<12288, 256, 0, stream>>>(query, key_, value, cq, ck, cv);
    cvt4_kernel<<<4096, 256, 0, stream>>>(w_q, w_k, w_v, w_o, wq, wk, wv, wo);

    dim3 blk(256);
    proj_gemm<<<dim3(32, 8, 3), blk, 0, stream>>>(cq, ck, cv, wq, wk, wv,
                                                  b_q, b_k, b_v, Qb, Kb, Vt);

    maskf_kernel<<<16, 256, 0, stream>>>(mask, mkf);  // after proj (cv reuse)

    attn_kernel<<<1024, blk, 0, stream>>>(Qb, Kb, Vt, mkf, Xb);

    out_gemm<<<dim3(32, 16), blk, 0, stream>>>(Xb, wo, b_o, (float*)d_out);
}

// Round 8
// 138.985 us; speedup vs baseline: 3.4383x; 1.0241x over previous
//
#include <hip/hip_runtime.h>
#include <hip/hip_bf16.h>

// MHA: B=2, S=2048, N_FEAT=1024, H=16, D=64
// r8: attn LDS 32KB (mask via pipelined register prefetch), tree-sum softmax;
//     proj z==2 epilogue transposed through LDS (coalesced V^T stores).

typedef float f32x4 __attribute__((ext_vector_type(4)));
typedef short bf16x8 __attribute__((ext_vector_type(8)));

typedef const __attribute__((address_space(1))) void* gas_ptr;
typedef __attribute__((address_space(3))) void* las_ptr;

#if __has_builtin(__builtin_amdgcn_exp2f)
#define EXP2(x) __builtin_amdgcn_exp2f(x)
#else
#define EXP2(x) exp2f(x)
#endif
#define LOG2E 1.4426950408889634f

static __device__ __forceinline__ short to_bf16s(float f) {
    __hip_bfloat16 h = __float2bfloat16(f);
    return __builtin_bit_cast(short, h);
}
// packed f32->bf16 (RNE), one instruction for two values
static __device__ __forceinline__ unsigned cvtpk(float lo, float hi) {
    unsigned r;
    asm("v_cvt_pk_bf16_f32 %0, %1, %2" : "=v"(r) : "v"(lo), "v"(hi));
    return r;
}

// ---------------- conversions ----------------
__global__ void cvt3_kernel(const float* __restrict__ s0, const float* __restrict__ s1,
                            const float* __restrict__ s2, short* __restrict__ d0,
                            short* __restrict__ d1, short* __restrict__ d2) {
    const int g = blockIdx.x;
    const int sel = g >> 12;
    const int i = (g & 4095) * 256 + threadIdx.x;
    const float* s = sel == 0 ? s0 : (sel == 1 ? s1 : s2);
    short* d = sel == 0 ? d0 : (sel == 1 ? d1 : d2);
    float4 v = reinterpret_cast<const float4*>(s)[i];
    short4 o;
    o.x = to_bf16s(v.x); o.y = to_bf16s(v.y); o.z = to_bf16s(v.z); o.w = to_bf16s(v.w);
    reinterpret_cast<short4*>(d)[i] = o;
}
__global__ void cvt4_kernel(const float* __restrict__ s0, const float* __restrict__ s1,
                            const float* __restrict__ s2, const float* __restrict__ s3,
                            short* __restrict__ d0, short* __restrict__ d1,
                            short* __restrict__ d2, short* __restrict__ d3) {
    const int g = blockIdx.x;
    const int sel = g >> 10;
    const int i = (g & 1023) * 256 + threadIdx.x;
    const float* s = sel == 0 ? s0 : (sel == 1 ? s1 : (sel == 2 ? s2 : s3));
    short* d = sel == 0 ? d0 : (sel == 1 ? d1 : (sel == 2 ? d2 : d3));
    float4 v = reinterpret_cast<const float4*>(s)[i];
    short4 o;
    o.x = to_bf16s(v.x); o.y = to_bf16s(v.y); o.z = to_bf16s(v.z); o.w = to_bf16s(v.w);
    reinterpret_cast<short4*>(d)[i] = o;
}

// mask -> additive log2-domain bias, PHI-PERMUTED within each 32-key chunk
__global__ void maskf_kernel(const int* __restrict__ mask, float* __restrict__ mf) {
    const int i = blockIdx.x * 256 + threadIdx.x;
    const int p = i & 31;
    const int phi = 8 * ((p >> 2) & 3) + 4 * (p >> 4) + (p & 3);
    mf[i] = mask[(i & ~31) | phi] ? (-10000.0f * LOG2E) : 0.0f;
}

// ---------------- GEMM core: dbuf 2-phase, rowpair-interleaved LDS ----------------
static __device__ __forceinline__ void stage_tile(
    short* sa, short* sb, const short* A, const short* W,
    int m0, int n0, int k0, int tid)
{
#pragma unroll
    for (int rnd = 0; rnd < 2; ++rnd) {
        const int t = rnd * 256 + tid;
        const int c2 = t & 7;
        const int row = 2 * (t >> 3) + (c2 & 1);
        const int col = (c2 >> 1) * 8;
        __builtin_amdgcn_global_load_lds((gas_ptr)(A + (long)(m0 + row) * 1024 + k0 + col),
                                         (las_ptr)(sa + t * 8), 16, 0, 0);
        __builtin_amdgcn_global_load_lds((gas_ptr)(W + (long)(n0 + row) * 1024 + k0 + col),
                                         (las_ptr)(sb + t * 8), 16, 0, 0);
    }
}

static __device__ __forceinline__ void gemm_compute(
    const short* sa, const short* sb, int wr, int wc, int aoff, f32x4 (&acc)[4][4])
{
    bf16x8 af[4], bfr[4];
#pragma unroll
    for (int i = 0; i < 4; ++i)
        af[i] = *reinterpret_cast<const bf16x8*>(sa + (wr + i * 16) * 32 + aoff);
#pragma unroll
    for (int j = 0; j < 4; ++j)
        bfr[j] = *reinterpret_cast<const bf16x8*>(sb + (wc + j * 16) * 32 + aoff);
#pragma unroll
    for (int i = 0; i < 4; ++i)
#pragma unroll
        for (int j = 0; j < 4; ++j)
            acc[i][j] = __builtin_amdgcn_mfma_f32_16x16x32_bf16(af[i], bfr[j], acc[i][j], 0, 0, 0);
}

// fused Q/K/V projection: blockIdx.z selects; Q scaled by 0.125*log2e;
// z==2 (V^T) epilogue goes through an LDS transpose for coalesced stores.
__global__ __launch_bounds__(256, 3) void proj_gemm(
    const short* __restrict__ A0, const short* __restrict__ A1, const short* __restrict__ A2,
    const short* __restrict__ W0, const short* __restrict__ W1, const short* __restrict__ W2,
    const float* __restrict__ bi0, const float* __restrict__ bi1, const float* __restrict__ bi2,
    short* __restrict__ o0, short* __restrict__ o1, short* __restrict__ o2)
{
    __shared__ __align__(16) short smem[17408];   // 34KB: staging (32KB) / xpose 128x136
    short* sA0 = smem;
    short* sA1 = smem + 4096;
    short* sB0 = smem + 8192;
    short* sB1 = smem + 12288;

    const int z = blockIdx.z;
    const short* A = z == 0 ? A0 : (z == 1 ? A1 : A2);
    const short* W = z == 0 ? W0 : (z == 1 ? W1 : W2);
    const float* bias = z == 0 ? bi0 : (z == 1 ? bi1 : bi2);
    short* outp = z == 0 ? o0 : (z == 1 ? o1 : o2);

    const int tid = threadIdx.x;
    const int w = tid >> 6, l = tid & 63;
    const int lr = l & 15, lh = l >> 4;
    const int m0 = blockIdx.x * 128, n0 = blockIdx.y * 128;
    const int wr = (w >> 1) * 64, wc = (w & 1) * 64;
    const int aoff = (lr >> 1) * 64 + (lr & 1) * 8 + lh * 16;

    f32x4 acc[4][4] = {};

    stage_tile(sA0, sB0, A, W, m0, n0, 0, tid);
    __syncthreads();
    for (int k0 = 0; k0 < 1024; k0 += 64) {
        stage_tile(sA1, sB1, A, W, m0, n0, k0 + 32, tid);
        gemm_compute(sA0, sB0, wr, wc, aoff, acc);
        __syncthreads();
        if (k0 + 64 < 1024)
            stage_tile(sA0, sB0, A, W, m0, n0, k0 + 64, tid);
        gemm_compute(sA1, sB1, wr, wc, aoff, acc);
        __syncthreads();
    }

    if (z != 2) {
        const float scl = (z == 0) ? 0.125f * LOG2E : 1.0f;
#pragma unroll
        for (int i = 0; i < 4; ++i) {
#pragma unroll
            for (int j = 0; j < 4; ++j) {
#pragma unroll
                for (int r = 0; r < 4; ++r) {
                    const int row = m0 + wr + i * 16 + lh * 4 + r;  // b*2048+s
                    const int col = n0 + wc + j * 16 + lr;          // h*64+d
                    const float v = (acc[i][j][r] + bias[col]) * scl;
                    const int b = row >> 11, s = row & 2047;
                    const int h = col >> 6, d = col & 63;
                    outp[(((long)(b * 16 + h)) * 2048 + s) * 64 + d] = to_bf16s(v);
                }
            }
        }
    } else {
        // V^T: write bf16 tile transposed into LDS [d_local][136], then
        // coalesced stores (lane = s-direction, 256B per instruction).
#pragma unroll
        for (int i = 0; i < 4; ++i) {
#pragma unroll
            for (int j = 0; j < 4; ++j) {
                const int dl = wc + j * 16 + lr;
                const int sl = wr + i * 16 + lh * 4;
                const float bv = bias[n0 + dl];
                const unsigned w0 = cvtpk(acc[i][j][0] + bv, acc[i][j][1] + bv);
                const unsigned w1 = cvtpk(acc[i][j][2] + bv, acc[i][j][3] + bv);
                uint2 pr; pr.x = w0; pr.y = w1;
                *reinterpret_cast<uint2*>(smem + dl * 136 + sl) = pr;
            }
        }
        __syncthreads();
        const int bb = m0 >> 11;
        const int s0 = m0 & 2047;
#pragma unroll 4
        for (int rr = 0; rr < 32; ++rr) {
            const int dl = w * 32 + rr;
            const int col = n0 + dl;
            const int hh = col >> 6, dd = col & 63;
            const unsigned val = *reinterpret_cast<const unsigned*>(smem + dl * 136 + 2 * l);
            *reinterpret_cast<unsigned*>(outp + ((long)(bb * 16 + hh) * 64 + dd) * 2048 + s0 + 2 * l) = val;
        }
    }
}

// output GEMM: 128x64 tile -> 512 blocks (2/CU), f32 epilogue
__global__ __launch_bounds__(256, 2) void out_gemm(
    const short* __restrict__ A, const short* __restrict__ W,
    const float* __restrict__ bias, float* __restrict__ outp)
{
    __shared__ __align__(16) short sa[2][4096];
    __shared__ __align__(16) short sb[2][2048];
    const int tid = threadIdx.x;
    const int w = tid >> 6, l = tid & 63;
    const int lr = l & 15, lh = l >> 4;
    const int m0 = blockIdx.x * 128, n0 = blockIdx.y * 64;
    const int wr = (w >> 1) * 64, wc = (w & 1) * 32;
    const int aoff = (lr >> 1) * 64 + (lr & 1) * 8 + lh * 16;

    f32x4 acc[4][2] = {};

    const int c2 = tid & 7;
    const int brow = 2 * (tid >> 3) + (c2 & 1);
    const int bcol = (c2 >> 1) * 8;

    auto stage = [&](short* pa, short* pb, int k0) {
#pragma unroll
        for (int rnd = 0; rnd < 2; ++rnd) {
            const int t = rnd * 256 + tid;
            const int cc = t & 7;
            const int row = 2 * (t >> 3) + (cc & 1);
            const int col = (cc >> 1) * 8;
            __builtin_amdgcn_global_load_lds((gas_ptr)(A + (long)(m0 + row) * 1024 + k0 + col),
                                             (las_ptr)(pa + t * 8), 16, 0, 0);
        }
        __builtin_amdgcn_global_load_lds((gas_ptr)(W + (long)(n0 + brow) * 1024 + k0 + bcol),
                                         (las_ptr)(pb + tid * 8), 16, 0, 0);
    };
    auto compute = [&](const short* pa, const short* pb) {
        bf16x8 af[4], bfr[2];
#pragma unroll
        for (int i = 0; i < 4; ++i)
            af[i] = *reinterpret_cast<const bf16x8*>(pa + (wr + i * 16) * 32 + aoff);
#pragma unroll
        for (int j = 0; j < 2; ++j)
            bfr[j] = *reinterpret_cast<const bf16x8*>(pb + (wc + j * 16) * 32 + aoff);
#pragma unroll
        for (int i = 0; i < 4; ++i)
#pragma unroll
            for (int j = 0; j < 2; ++j)
                acc[i][j] = __builtin_amdgcn_mfma_f32_16x16x32_bf16(af[i], bfr[j], acc[i][j], 0, 0, 0);
    };

    stage(sa[0], sb[0], 0);
    __syncthreads();
    for (int k0 = 0; k0 < 1024; k0 += 64) {
        stage(sa[1], sb[1], k0 + 32);
        compute(sa[0], sb[0]);
        __syncthreads();
        if (k0 + 64 < 1024)
            stage(sa[0], sb[0], k0 + 64);
        compute(sa[1], sb[1]);
        __syncthreads();
    }

#pragma unroll
    for (int i = 0; i < 4; ++i)
#pragma unroll
        for (int j = 0; j < 2; ++j)
#pragma unroll
            for (int r = 0; r < 4; ++r) {
                const int row = m0 + wr + i * 16 + lh * 4 + r;
                const int col = n0 + wc + j * 16 + lr;
                outp[(long)row * 1024 + col] = acc[i][j][r] + bias[col];
            }
}

// ---------------- flash attention v8 ----------------
// 1024 blocks XCD-remapped (4 heads/XCD); 4 waves x 16 q-rows; LDS 32KB ->
// >=4 blocks/CU. Mask bias via software-pipelined register prefetch (L2-hot).
// K rows phi-permuted; PV full-K MFMA with in-register P; tree-reduced softmax.

static __device__ __forceinline__ void stage_kv(
    short* ldsKb, short* ldsVb, const short* Kg, const short* Vg,
    int key0, int w, int srow, int prow, int schunk)
{
    __builtin_amdgcn_global_load_lds((gas_ptr)(Kg + (long)(key0 + prow) * 64 + schunk * 8),
                                     (las_ptr)(ldsKb + w * 512), 16, 0, 0);
    __builtin_amdgcn_global_load_lds((gas_ptr)(Kg + (long)(key0 + 32 + prow) * 64 + schunk * 8),
                                     (las_ptr)(ldsKb + 2048 + w * 512), 16, 0, 0);
    __builtin_amdgcn_global_load_lds((gas_ptr)(Vg + (long)srow * 2048 + key0 + schunk * 8),
                                     (las_ptr)(ldsVb + w * 512), 16, 0, 0);
    __builtin_amdgcn_global_load_lds((gas_ptr)(Vg + (long)(srow + 32) * 2048 + key0 + schunk * 8),
                                     (las_ptr)(ldsVb + 2048 + w * 512), 16, 0, 0);
}

static __device__ __forceinline__ void attn_step(
    const short* __restrict__ Kbuf, const short* __restrict__ Vbuf,
    const f32x4 (&mb)[4],
    const bf16x8 qf0, const bf16x8 qf1, int lr, int lh, int sw,
    float& mreg, float& lsum, f32x4 (&ao)[4])
{
    // swapped QK^T: lane holds q=lr, physical key-slot = 16s + 4lh + r;
    // mask bias is the MFMA C-init.
    f32x4 sc[4];
#pragma unroll
    for (int s = 0; s < 4; ++s) {
        const short* kb = Kbuf + (s * 16 + lr) * 64;
        bf16x8 k0 = *reinterpret_cast<const bf16x8*>(kb + (((lh * 16) ^ sw) >> 1));
        bf16x8 k1 = *reinterpret_cast<const bf16x8*>(kb + (((64 + lh * 16) ^ sw) >> 1));
        sc[s] = __builtin_amdgcn_mfma_f32_16x16x32_bf16(k0, qf0, mb[s], 0, 0, 0);
        sc[s] = __builtin_amdgcn_mfma_f32_16x16x32_bf16(k1, qf1, sc[s], 0, 0, 0);
    }

    float m0 = fmaxf(fmaxf(sc[0][0], sc[0][1]), fmaxf(sc[0][2], sc[0][3]));
    float m1 = fmaxf(fmaxf(sc[1][0], sc[1][1]), fmaxf(sc[1][2], sc[1][3]));
    float m2 = fmaxf(fmaxf(sc[2][0], sc[2][1]), fmaxf(sc[2][2], sc[2][3]));
    float m3 = fmaxf(fmaxf(sc[3][0], sc[3][1]), fmaxf(sc[3][2], sc[3][3]));
    float t = fmaxf(fmaxf(m0, m1), fmaxf(m2, m3));
    t = fmaxf(t, __shfl_xor(t, 16));
    t = fmaxf(t, __shfl_xor(t, 32));
    // defer-max: rescale only when max grew by > 8 (P bounded by 2^8)
    if (__any(t > mreg + 8.0f)) {
        const float mn = fmaxf(mreg, t);
        const float sf = EXP2(mreg - mn);
        lsum *= sf;
#pragma unroll
        for (int d4 = 0; d4 < 4; ++d4) ao[d4] *= sf;
        mreg = mn;
    }
    float e[16];
#pragma unroll
    for (int s = 0; s < 4; ++s)
#pragma unroll
        for (int r = 0; r < 4; ++r)
            e[s * 4 + r] = EXP2(sc[s][r] - mreg);
    // depth-4 tree sum
    const float e0 = (e[0] + e[1]) + (e[2] + e[3]);
    const float e1 = (e[4] + e[5]) + (e[6] + e[7]);
    const float e2 = (e[8] + e[9]) + (e[10] + e[11]);
    const float e3 = (e[12] + e[13]) + (e[14] + e[15]);
    float ps = (e0 + e1) + (e2 + e3);
    ps += __shfl_xor(ps, 16);
    ps += __shfl_xor(ps, 32);
    lsum += ps;

    // pack P into the two 16x16x32 B-frags (chunk c covers s-tiles 2c, 2c+1)
    unsigned pw[8];
#pragma unroll
    for (int i = 0; i < 8; ++i) pw[i] = cvtpk(e[2 * i], e[2 * i + 1]);
    const bf16x8 pb0 = __builtin_bit_cast(bf16x8, *(ulonglong2*)&pw[0]);
    const bf16x8 pb1 = __builtin_bit_cast(bf16x8, *(ulonglong2*)&pw[4]);

    // PV via 16x16x32: A = V^T rows (linear keys), B = pb (in-register)
#pragma unroll
    for (int c = 0; c < 2; ++c) {
        const bf16x8 pbc = c == 0 ? pb0 : pb1;
#pragma unroll
        for (int d4 = 0; d4 < 4; ++d4) {
            const short* vb = Vbuf + (d4 * 16 + lr) * 64;
            bf16x8 vf = *reinterpret_cast<const bf16x8*>(vb + (((c * 64 + lh * 16) ^ sw) >> 1));
            ao[d4] = __builtin_amdgcn_mfma_f32_16x16x32_bf16(vf, pbc, ao[d4], 0, 0, 0);
        }
    }
}

__global__ __launch_bounds__(256, 4) void attn_kernel(
    const short* __restrict__ Q, const short* __restrict__ Kmat,
    const short* __restrict__ Vt, const float* __restrict__ maskf,
    short* __restrict__ X)
{
    __shared__ __align__(16) short ldsK[2][4096];
    __shared__ __align__(16) short ldsV[2][4096];

    const int id = blockIdx.x;
    const int slot = id >> 3;
    const int bh = (id & 7) * 4 + (slot >> 5);   // XCD (id&7) serves heads 4x..4x+3
    const int q0 = (slot & 31) * 64;
    const int b = bh >> 4, h = bh & 15;
    const int w = threadIdx.x >> 6, l = threadIdx.x & 63;
    const int lr = l & 15, lh = l >> 4;
    const int sw = (lr & 7) << 4;                // read-side XOR swizzle (bytes)

    const int srow = w * 8 + (l >> 3);           // 0..31
    const int schunk = (l & 7) ^ (srow & 7);
    const int prow = 8 * ((srow >> 2) & 3) + 4 * (srow >> 4) + (srow & 3);  // phi

    const short* Kg = Kmat + (long)bh * 2048 * 64;
    const short* Vg = Vt + (long)bh * 64 * 2048;
    const float* mfp = maskf + b * 2048 + lh * 4;

    // Q B-frag (Q pre-scaled by 0.125*log2e at projection): wave owns 16 q-rows
    const short* Qp = Q + ((long)bh * 2048 + q0 + w * 16 + lr) * 64 + lh * 8;
    const bf16x8 qf0 = *reinterpret_cast<const bf16x8*>(Qp);
    const bf16x8 qf1 = *reinterpret_cast<const bf16x8*>(Qp + 32);

    float mreg = -1e30f, lsum = 0.f;
    f32x4 ao[4] = {};

    // mask-bias register prefetch, one 64-key step ahead
    f32x4 mbA[4], mbB[4];
#pragma unroll
    for (int s = 0; s < 4; ++s)
        mbA[s] = *reinterpret_cast<const f32x4*>(mfp + s * 16);

    stage_kv(ldsK[0], ldsV[0], Kg, Vg, 0, w, srow, prow, schunk);
    __syncthreads();

    for (int tt = 0; tt < 16; ++tt) {
        const int key0 = tt * 128;
#pragma unroll
        for (int s = 0; s < 4; ++s)
            mbB[s] = *reinterpret_cast<const f32x4*>(mfp + key0 + 64 + s * 16);
        stage_kv(ldsK[1], ldsV[1], Kg, Vg, key0 + 64, w, srow, prow, schunk);
        attn_step(ldsK[0], ldsV[0], mbA, qf0, qf1, lr, lh, sw, mreg, lsum, ao);
        __syncthreads();
        if (tt < 15) {
#pragma unroll
            for (int s = 0; s < 4; ++s)
                mbA[s] = *reinterpret_cast<const f32x4*>(mfp + key0 + 128 + s * 16);
            stage_kv(ldsK[0], ldsV[0], Kg, Vg, key0 + 128, w, srow, prow, schunk);
        }
        attn_step(ldsK[1], ldsV[1], mbB, qf0, qf1, lr, lh, sw, mreg, lsum, ao);
        __syncthreads();
    }

    // lane holds O^T[d = d4*16 + lh*4 + r][q = lr]
    const float inv = 1.0f / fmaxf(lsum, 1e-30f);
    const int s = q0 + w * 16 + lr;
    short* Xp = X + ((long)b * 2048 + s) * 1024 + h * 64 + lh * 4;
#pragma unroll
    for (int d4 = 0; d4 < 4; ++d4) {
        uint2 o;
        o.x = cvtpk(ao[d4][0] * inv, ao[d4][1] * inv);
        o.y = cvtpk(ao[d4][2] * inv, ao[d4][3] * inv);
        *reinterpret_cast<uint2*>(Xp + d4 * 16) = o;
    }
}

// ---------------- launch ----------------
extern "C" void kernel_launch(void* const* d_in, const int* in_sizes, int n_in,
                              void* d_out, int out_size, void* d_ws, size_t ws_size,
                              hipStream_t stream) {
    const float* query = (const float*)d_in[0];
    const float* key_  = (const float*)d_in[1];
    const float* value = (const float*)d_in[2];
    const int*   mask  = (const int*)d_in[3];
    const float* w_q = (const float*)d_in[4];
    const float* b_q = (const float*)d_in[5];
    const float* w_k = (const float*)d_in[6];
    const float* b_k = (const float*)d_in[7];
    const float* w_v = (const float*)d_in[8];
    const float* b_v = (const float*)d_in[9];
    const float* w_o = (const float*)d_in[10];
    const float* b_o = (const float*)d_in[11];

    const long SEQ = 4194304;  // 4096*1024 elements
    const long WSZ = 1048576;  // 1024*1024
    short* ws = (short*)d_ws;
    short* cq = ws;
    short* ck = cq + SEQ;
    short* cv = ck + SEQ;
    short* wq = cv + SEQ;
    short* wk = wq + WSZ;
    short* wv = wk + WSZ;
    short* wo = wv + WSZ;
    short* Qb = wo + WSZ;      // (B,H,S,64), pre-scaled by 0.125*log2e
    short* Kb = Qb + SEQ;
    short* Vt = Kb + SEQ;      // (B,H,64,S)
    short* Xb = cq;            // reuse: cq dead after projections
    float* mkf = (float*)cv;   // reuse: cv dead after projections

    cvt3_kernel<<<12288, 256, 0, stream>>>(query, key_, value, cq, ck, cv);
    cvt4_kernel<<<4096, 256, 0, stream>>>(w_q, w_k, w_v, w_o, wq, wk, wv, wo);

    dim3 blk(256);
    proj_gemm<<<dim3(32, 8, 3), blk, 0, stream>>>(cq, ck, cv, wq, wk, wv,
                                                  b_q, b_k, b_v, Qb, Kb, Vt);

    maskf_kernel<<<16, 256, 0, stream>>>(mask, mkf);  // after proj (cv reuse)

    attn_kernel<<<1024, blk, 0, stream>>>(Qb, Kb, Vt, mkf, Xb);

    out_gemm<<<dim3(32, 16), blk, 0, stream>>>(Xb, wo, b_o, (float*)d_out);
}